// Round 13
// baseline (9000.050 us; speedup 1.0000x reference)
//
#include <hip/hip_runtime.h>
#include <math.h>

// IDE state-space Kalman filter, MI355X (gfx950). Round 20:
// R19 (7806 us) + two idle-lane/parallelism fixes, zero new barriers:
// - trinv partial hoist: I-step kb-1 of chains J=0,1,2 runs in P1(kb) on
//   waves 2-13 (idle there; needs only columns <= kb-1 TRSM'd, own prior
//   M writes, Linv_{kb-1} from P2(kb-1) -- all barrier-ordered). Residual
//   trinv phase rebalanced to ~14 block-dots/grp (was 28 max). ONE
//   noinline step function (R12 lesson: no inlined fan).
// - MC y = M v parallelized 8 threads/row (plain GEMV, masked upper reads,
//   shfl_xor reduce; seg0 writes yv + logdet). Chain 127 -> ~19.

#define SQ 64
#define DQ 128
#define TQ 128
#define BQ 16
#define LDP 132           // fp32 row stride
#define LDB 136           // bf16 row stride (16B-aligned rows, 2-way banks)
#define WFLOATS 17408     // W region: 69632 B (Tb + Ab2 bf16 when dead)
#define NTH 1024
#define LOG2PI 1.8378770664093454f

#define SMEM_FLOATS 35472

typedef __attribute__((ext_vector_type(8))) short bf16x8;
typedef __attribute__((ext_vector_type(4))) float f32x4;

__device__ __forceinline__ void lds_fence() {
  __asm__ volatile("s_waitcnt lgkmcnt(0)" ::: "memory");
}

__device__ __forceinline__ unsigned short f2bf(float f) {
  unsigned u = __float_as_uint(f);
  u += 0x7fffu + ((u >> 16) & 1u);
  return (unsigned short)(u >> 16);
}
__device__ __forceinline__ uint4 pack8(const float* v) {
  uint4 r;
  r.x = (unsigned)f2bf(v[0]) | ((unsigned)f2bf(v[1]) << 16);
  r.y = (unsigned)f2bf(v[2]) | ((unsigned)f2bf(v[3]) << 16);
  r.z = (unsigned)f2bf(v[4]) | ((unsigned)f2bf(v[5]) << 16);
  r.w = (unsigned)f2bf(v[6]) | ((unsigned)f2bf(v[7]) << 16);
  return r;
}

__device__ __forceinline__ float block_reduce_sum(float v, float* red) {
  #pragma unroll
  for (int off = 32; off > 0; off >>= 1) v += __shfl_down(v, off);
  const int tid = threadIdx.x;
  if ((tid & 63) == 0) red[tid >> 6] = v;
  __syncthreads();
  v = 0.0f;
  #pragma unroll
  for (int w = 0; w < NTH / 64; w++) v += red[w];
  __syncthreads();
  return v;
}

// 16x16 Cholesky, factor only (register/shfl resident on one wave).
__device__ __forceinline__ void chol16_f(float* __restrict__ Wf,
                                         float* __restrict__ mdiag,
                                         int b0, int lane) {
  float a[16];
  if (lane < 16) {
    const float4* rp = (const float4*)(Wf + (b0 + lane) * LDP + b0);
    float4 q0 = rp[0], q1 = rp[1], q2v = rp[2], q3 = rp[3];
    a[0]=q0.x; a[1]=q0.y; a[2]=q0.z; a[3]=q0.w;
    a[4]=q1.x; a[5]=q1.y; a[6]=q1.z; a[7]=q1.w;
    a[8]=q2v.x; a[9]=q2v.y; a[10]=q2v.z; a[11]=q2v.w;
    a[12]=q3.x; a[13]=q3.y; a[14]=q3.z; a[15]=q3.w;
  } else {
    #pragma unroll
    for (int i = 0; i < 16; i++) a[i] = 1.0f;
  }
  float myrinv = 1.0f;
  #pragma unroll
  for (int j = 0; j < 16; j++) {
    float dj = __shfl(a[j], j);
    float rinv = rsqrtf(dj);
    float lij = a[j] * rinv;
    a[j] = lij;
    if (lane == j) myrinv = rinv;
    #pragma unroll
    for (int k = j + 1; k < 16; k++) {
      float lkj = __shfl(lij, k);
      a[k] = fmaf(-lij, lkj, a[k]);
    }
  }
  if (lane < 16) {
    float4* rp = (float4*)(Wf + (b0 + lane) * LDP + b0);
    rp[0] = make_float4(a[0], a[1], a[2], a[3]);
    rp[1] = make_float4(a[4], a[5], a[6], a[7]);
    rp[2] = make_float4(a[8], a[9], a[10], a[11]);
    rp[3] = make_float4(a[12], a[13], a[14], a[15]);
    mdiag[b0 + lane] = myrinv;
  }
}

// trinv I-steps [I0, I1) for chain (J, pass): columns {4g+pass} of M(*,J).
// Linv_J / Linv_I (I<7) read from hoisted diag uppers; I=7 falls back to
// dependent substitution. noinline: single code instance (R12 lesson).
__device__ __attribute__((noinline)) void trinv_steps(
    float* __restrict__ Wf, const float* __restrict__ mdiag,
    int J, int pass, int lane, int I0, int I1) {
  const int c16 = lane & 15;
  const int j16 = 4 * (lane >> 4) + pass;
  const int sh = lane & 48;
  const float md = mdiag[J * 16 + j16];
  const float* Mrow = Wf + (J * 16 + j16) * LDP + J * 16;
  #pragma unroll 1
  for (int I = I0; I < I1; I++) {
    const float* Lrow = Wf + (I * 16 + c16) * LDP + J * 16;
    float g = 0.0f;
    // K = J: masked Linv_J read (hoisted upper + mdiag diagonal)
    #pragma unroll
    for (int c4 = 0; c4 < 4; c4++) {
      float4 lv = *(const float4*)&Lrow[c4 * 4];
      float4 mq = *(const float4*)&Mrow[c4 * 4];
      float w0 = (c4*4+0 > j16) ? mq.x : ((c4*4+0 == j16) ? md : 0.0f);
      float w1 = (c4*4+1 > j16) ? mq.y : ((c4*4+1 == j16) ? md : 0.0f);
      float w2 = (c4*4+2 > j16) ? mq.z : ((c4*4+2 == j16) ? md : 0.0f);
      float w3 = (c4*4+3 > j16) ? mq.w : ((c4*4+3 == j16) ? md : 0.0f);
      g = fmaf(lv.x, w0, g); g = fmaf(lv.y, w1, g);
      g = fmaf(lv.z, w2, g); g = fmaf(lv.w, w3, g);
    }
    for (int K = J + 1; K < I; K++) {
      const float* LK = Lrow + (K - J) * 16;
      const float* MK = Wf + (J * 16 + j16) * LDP + K * 16;
      #pragma unroll
      for (int c4 = 0; c4 < 4; c4++) {
        float4 lv = *(const float4*)&LK[c4 * 4];
        float4 mq = *(const float4*)&MK[c4 * 4];
        g = fmaf(lv.x, mq.x, g); g = fmaf(lv.y, mq.y, g);
        g = fmaf(lv.z, mq.z, g); g = fmaf(lv.w, mq.w, g);
      }
    }
    if (I < 7) {
      // apply hoisted Linv_I: independent shfls of original g (fast path)
      float s = mdiag[I * 16 + c16] * g;
      #pragma unroll
      for (int k = 0; k < 15; k++) {
        float gk = __shfl(g, sh | k);
        if (k < c16) {
          float u = Wf[(I * 16 + k) * LDP + I * 16 + c16];
          s = fmaf(u, gk, s);
        }
      }
      Wf[(J * 16 + j16) * LDP + (I * 16 + c16)] = -s;
    } else {
      // I = 7: Linv_7 unavailable; dependent forward substitution
      float row2[16];
      {
        const float4* rp2 = (const float4*)(Wf + (I * 16 + c16) * LDP + I * 16);
        float4 a0 = rp2[0], a1 = rp2[1], a2 = rp2[2], a3 = rp2[3];
        row2[0]=a0.x; row2[1]=a0.y; row2[2]=a0.z; row2[3]=a0.w;
        row2[4]=a1.x; row2[5]=a1.y; row2[6]=a1.z; row2[7]=a1.w;
        row2[8]=a2.x; row2[9]=a2.y; row2[10]=a2.z; row2[11]=a2.w;
        row2[12]=a3.x; row2[13]=a3.y; row2[14]=a3.z; row2[15]=a3.w;
      }
      float sv = g;
      #pragma unroll
      for (int k = 0; k < 16; k++) {
        if (c16 == k) sv *= mdiag[I * 16 + k];
        float sk = __shfl(sv, sh | k);
        if (c16 > k) sv = fmaf(-row2[k], sk, sv);
      }
      Wf[(J * 16 + j16) * LDP + (I * 16 + c16)] = -sv;
    }
    lds_fence();
  }
}

extern "C" __global__ __launch_bounds__(NTH, 4)
void ide_kf_kernel(const float* __restrict__ z_seq,
                   const float* __restrict__ site_lon,
                   const float* __restrict__ site_lat,
                   const float* __restrict__ mu_seq,
                   const float* __restrict__ sigma_seq,
                   const float* __restrict__ log_q,
                   const float* __restrict__ log_r,
                   const float* __restrict__ log_p0,
                   const float* __restrict__ log_damp,
                   const float* __restrict__ init_mean,
                   const float* __restrict__ coupling_raw,
                   float* __restrict__ ws) {
  extern __shared__ float smem[];
  float* Wf     = smem;                  // 17408 floats (fp32 chol space)
  float* B1f    = Wf + WFLOATS;          // 8704 floats (Mtb bf16 / Lhi)
  float* B2f    = B1f + 8704;            // 8704 floats (Pb bf16 / Llo)
  float* coords = B2f + 8704;            // 128
  float* mv     = coords + 128;          // 128 (posterior mean)
  float* vv     = mv + DQ;               // 128
  float* yv     = vv + DQ;               // 128
  float* mdiag  = yv + DQ;               // 128
  float* red    = mdiag + DQ;            // 16

  unsigned short* Tb  = (unsigned short*)Wf;            // bf16, stride LDB
  unsigned short* Ab2 = (unsigned short*)Wf + 17408;    // A bf16 (Wf upper)
  unsigned short* Mtb = (unsigned short*)B1f;           // M^T bf16
  unsigned short* Pb  = (unsigned short*)B2f;           // P bf16 (symmetric)
  unsigned short* Lhi = (unsigned short*)B1f;           // chol L hi (Mtb dead)
  unsigned short* Llo = (unsigned short*)B2f;           // chol L lo (Pb dead)

  const int tid = threadIdx.x;
  const int lane = tid & 63;
  const int wave = tid >> 6;
  const int rb = wave >> 1, ch = wave & 1;
  const int m16 = lane & 15, quad = lane >> 4;
  const int grp = wave >> 2, pass = wave & 3;
  const int b = blockIdx.x;
  float* nll_out = ws;

  const float r2 = __expf(2.0f * log_r[0]);
  const float q2 = __expf(2.0f * log_q[0]);
  const float p0sq = __expf(2.0f * log_p0[0]);
  const float damping = __expf(log_damp[0]);
  const float cpl00 = 1.0f + 0.25f * tanhf(coupling_raw[0]);
  const float cpl01 = 0.25f * tanhf(coupling_raw[1]);
  const float cpl10 = 0.25f * tanhf(coupling_raw[2]);
  const float cpl11 = 1.0f + 0.25f * tanhf(coupling_raw[3]);

  // ---- lon/lat projection ----
  float myLon = (tid < SQ) ? site_lon[tid] : 0.0f;
  float myLat = (tid < SQ) ? site_lat[tid] : 0.0f;
  float lat0 = block_reduce_sum(myLat, red) * (1.0f / 64.0f);
  float lon0 = block_reduce_sum(myLon, red) * (1.0f / 64.0f);
  if (tid < SQ) {
    const float km = 111.32f;
    float cs = cosf(lat0 * 0.017453292519943295f);
    coords[2 * tid]     = (myLon - lon0) * (km * cs);
    coords[2 * tid + 1] = (myLat - lat0) * km;
  }
  __syncthreads();
  float dsum = 0.0f, dcnt = 0.0f;
  for (int idx = tid; idx < SQ * SQ; idx += NTH) {
    int i = idx >> 6, j = idx & 63;
    float dx = coords[2 * i] - coords[2 * j];
    float dy = coords[2 * i + 1] - coords[2 * j + 1];
    float d = sqrtf(dx * dx + dy * dy + 1e-12f);
    dsum += d;
    if (d > 1e-6f) dcnt += 1.0f;
  }
  dsum = block_reduce_sum(dsum, red);
  dcnt = block_reduce_sum(dcnt, red);
  float scale = dsum / fmaxf(dcnt, 1.0f);
  float sdiv = 1.0f / fmaxf(scale, 1e-6f);
  if (tid < SQ) { coords[2 * tid] *= sdiv; coords[2 * tid + 1] *= sdiv; }

  // ---- init: Wf = (p0sq+r2) I, mv = init_mean ----
  for (int e = tid; e < WFLOATS / 4; e += NTH)
    ((float4*)Wf)[e] = make_float4(0.0f, 0.0f, 0.0f, 0.0f);
  for (int e = tid; e < 8704 / 4; e += NTH)
    ((float4*)B2f)[e] = make_float4(0.0f, 0.0f, 0.0f, 0.0f);
  __syncthreads();
  if (tid < DQ) {
    Wf[tid * LDP + tid] = p0sq + r2;
    mv[tid] = init_mean[tid];
  }
  __syncthreads();

  float nllp = 0.0f;

  #pragma unroll 1
  for (int t = 0; t < TQ; t++) {
    const float* zt = z_seq + ((size_t)b * TQ + t) * DQ;

    if (t > 0) {
      // ---- PHASE T: mfma T = A*P -> Tb (single barrier) ----
      {
        f32x4 acc[4];
        #pragma unroll
        for (int c = 0; c < 4; c++) acc[c] = (f32x4){0.0f, 0.0f, 0.0f, 0.0f};
        #pragma unroll
        for (int ks = 0; ks < 4; ks++) {
          const int ko = 32 * ks + 8 * quad;
          bf16x8 a = *(const bf16x8*)(Ab2 + (16 * rb + m16) * LDB + ko);
          #pragma unroll
          for (int ct = 0; ct < 4; ct++) {
            bf16x8 bb = *(const bf16x8*)(Pb + (64 * ch + 16 * ct + m16) * LDB + ko);
            acc[ct] = __builtin_amdgcn_mfma_f32_16x16x32_bf16(a, bb, acc[ct], 0, 0, 0);
          }
        }
        #pragma unroll
        for (int ct = 0; ct < 4; ct++)
          #pragma unroll
          for (int reg = 0; reg < 4; reg++)
            Tb[(16 * rb + 4 * quad + reg) * LDB + 64 * ch + 16 * ct + m16] =
                f2bf(acc[ct][reg]);
        __syncthreads();
      }

      // ---- PHASE P': part1: Sm MFMA + m-GEMV (idle waves 1,3);
      //      midbar; part2: fp32 Wf + wave0 chol16_f(0) + vv ----
      {
        const int ctmax = rb - 4 * ch;
        f32x4 acc[4];
        #pragma unroll
        for (int c = 0; c < 4; c++) acc[c] = (f32x4){0.0f, 0.0f, 0.0f, 0.0f};
        const bool gemv_wave = (wave == 1 || wave == 3);
        const int grow = (wave == 1) ? lane : 64 + lane;
        float newm = 0.0f;
        if (ctmax >= 0) {
          #pragma unroll
          for (int ks = 0; ks < 4; ks++) {
            const int ko = 32 * ks + 8 * quad;
            bf16x8 a = *(const bf16x8*)(Tb + (16 * rb + m16) * LDB + ko);
            #pragma unroll
            for (int ct = 0; ct < 4; ct++) {
              if (ct <= ctmax) {
                bf16x8 bb = *(const bf16x8*)(Ab2 + (64 * ch + 16 * ct + m16) * LDB + ko);
                acc[ct] = __builtin_amdgcn_mfma_f32_16x16x32_bf16(a, bb, acc[ct], 0, 0, 0);
              }
            }
          }
        } else if (gemv_wave) {
          const unsigned* ar = (const unsigned*)(Ab2 + grow * LDB);
          #pragma unroll 8
          for (int k2 = 0; k2 < 64; k2++) {
            unsigned p = ar[k2];
            newm = fmaf(__uint_as_float(p << 16), mv[2 * k2], newm);
            newm = fmaf(__uint_as_float(p & 0xffff0000u), mv[2 * k2 + 1], newm);
          }
        }
        __syncthreads();   // Tb/Ab2 reads done
        if (ctmax >= 0) {
          #pragma unroll
          for (int ct = 0; ct < 4; ct++) {
            if (ct <= ctmax) {
              #pragma unroll
              for (int reg = 0; reg < 4; reg++) {
                const int rg = 16 * rb + 4 * quad + reg;
                const int cgl = 64 * ch + 16 * ct + m16;
                Wf[rg * LDP + cgl] = acc[ct][reg] + ((rg == cgl) ? (q2 + r2) : 0.0f);
              }
            }
          }
        }
        if (gemv_wave) vv[grow] = zt[grow] - newm;
        if (wave == 0) {
          lds_fence();
          chol16_f(Wf, mdiag, 0, lane);
        }
        __syncthreads();
      }
    }

    if (t == 0) {
      // ---- K0 (t=0 only): wave0 chol diag0 ; vv ----
      if (tid < 64) {
        chol16_f(Wf, mdiag, 0, lane);
      } else if (tid < 192) {
        const int i = tid - 64;
        vv[i] = zt[i] - mv[i];
      }
      __syncthreads();
    }

    // ---- chol: LEFT-LOOKING, split-bf16 MFMA column updates ----
    #pragma unroll 1
    for (int kb = 0; kb < 7; kb++) {
      const int b0k = kb * 16, base = b0k + 16, nbelow = DQ - base;
      // P1: TRSM rows base..127 vs diag kb + pack hi/lo + zero next slot;
      //     waves 2-13: hoisted trinv I-step kb-1 for chains J=0,1,2.
      if (tid < nbelow) {
        const int r = base + tid;
        float* wr = Wf + r * LDP + b0k;
        float w[16];
        #pragma unroll
        for (int u4 = 0; u4 < 4; u4++) {
          float4 w4 = *(const float4*)&wr[u4 * 4];
          w[u4*4] = w4.x; w[u4*4+1] = w4.y; w[u4*4+2] = w4.z; w[u4*4+3] = w4.w;
        }
        #pragma unroll
        for (int j = 0; j < 16; j++) {
          float s = w[j];
          #pragma unroll
          for (int l = 0; l < 16; l++) {
            if (l < j) s = fmaf(-w[l], Wf[(b0k + j) * LDP + b0k + l], s);
          }
          w[j] = s * mdiag[b0k + j];
        }
        #pragma unroll
        for (int u4 = 0; u4 < 4; u4++)
          *(float4*)&wr[u4 * 4] =
              make_float4(w[u4*4], w[u4*4+1], w[u4*4+2], w[u4*4+3]);
        // split-bf16 pack: w = hi + lo
        unsigned short hs[16]; float lo[16];
        #pragma unroll
        for (int u = 0; u < 16; u++) {
          hs[u] = f2bf(w[u]);
          lo[u] = w[u] - __uint_as_float(((unsigned)hs[u]) << 16);
        }
        uint4 h0, h1;
        h0.x = hs[0] | ((unsigned)hs[1] << 16);   h0.y = hs[2] | ((unsigned)hs[3] << 16);
        h0.z = hs[4] | ((unsigned)hs[5] << 16);   h0.w = hs[6] | ((unsigned)hs[7] << 16);
        h1.x = hs[8] | ((unsigned)hs[9] << 16);   h1.y = hs[10] | ((unsigned)hs[11] << 16);
        h1.z = hs[12] | ((unsigned)hs[13] << 16); h1.w = hs[14] | ((unsigned)hs[15] << 16);
        unsigned short* hr = Lhi + r * LDB + b0k;
        unsigned short* lr = Llo + r * LDB + b0k;
        *(uint4*)(hr) = h0; *(uint4*)(hr + 8) = h1;
        *(uint4*)(lr) = pack8(lo); *(uint4*)(lr + 8) = pack8(lo + 8);
        // zero next panel's column slot (odd-K chunk overshoot reads zeros)
        const uint4 z4 = make_uint4(0u, 0u, 0u, 0u);
        *(uint4*)(hr + 16) = z4; *(uint4*)(hr + 24) = z4;
        *(uint4*)(lr + 16) = z4; *(uint4*)(lr + 24) = z4;
      } else if (wave >= 2 && wave <= 13) {
        const int hJ = (wave - 2) >> 2;       // 0,1,2
        if (kb >= hJ + 2)
          trinv_steps(Wf, mdiag, hJ, (wave - 2) & 3, lane, kb - 1, kb);
      }
      __syncthreads();
      // P2: U(kb+1) tiles; wave0 diag + chol16; waves 8-11: Linv_kb solve
      if (wave <= 6 - kb) {
        const int bi = kb + 1 + wave;
        const int nch = (kb + 2) >> 1;   // ceil(16(kb+1)/32)
        f32x4 acc = (f32x4){0.0f, 0.0f, 0.0f, 0.0f};
        for (int c = 0; c < nch; c++) {
          const int ko = 32 * c + 8 * quad;
          bf16x8 ahi = *(const bf16x8*)(Lhi + (16 * bi + m16) * LDB + ko);
          bf16x8 alo = *(const bf16x8*)(Llo + (16 * bi + m16) * LDB + ko);
          bf16x8 bhi = *(const bf16x8*)(Lhi + (base + m16) * LDB + ko);
          bf16x8 blo = *(const bf16x8*)(Llo + (base + m16) * LDB + ko);
          acc = __builtin_amdgcn_mfma_f32_16x16x32_bf16(ahi, bhi, acc, 0, 0, 0);
          acc = __builtin_amdgcn_mfma_f32_16x16x32_bf16(ahi, blo, acc, 0, 0, 0);
          acc = __builtin_amdgcn_mfma_f32_16x16x32_bf16(alo, bhi, acc, 0, 0, 0);
        }
        #pragma unroll
        for (int reg = 0; reg < 4; reg++)
          Wf[(16 * bi + 4 * quad + reg) * LDP + base + m16] -= acc[reg];
        if (wave == 0) {
          lds_fence();
          chol16_f(Wf, mdiag, base, lane);
        }
      } else if (wave >= 8 && wave <= 11) {
        // Linv_kb column solve (pass = wave-8) -> diag-kb upper.
        const int c16 = lane & 15;
        const int j16s = 4 * (lane >> 4) + (wave - 8);
        const int sh = lane & 48;
        float row[16];
        const float4* rp = (const float4*)(Wf + (b0k + c16) * LDP + b0k);
        float4 a0 = rp[0], a1 = rp[1], a2 = rp[2], a3 = rp[3];
        row[0]=a0.x; row[1]=a0.y; row[2]=a0.z; row[3]=a0.w;
        row[4]=a1.x; row[5]=a1.y; row[6]=a1.z; row[7]=a1.w;
        row[8]=a2.x; row[9]=a2.y; row[10]=a2.z; row[11]=a2.w;
        row[12]=a3.x; row[13]=a3.y; row[14]=a3.z; row[15]=a3.w;
        float s = (c16 == j16s) ? 1.0f : 0.0f;
        #pragma unroll
        for (int k = 0; k < 16; k++) {
          if (c16 == k) s *= mdiag[b0k + k];
          float sk = __shfl(s, sh | k);
          if (c16 > k) s = fmaf(-row[k], sk, s);
        }
        if (c16 > j16s) Wf[(b0k + j16s) * LDP + (b0k + c16)] = s;
      }
      __syncthreads();
    }

    // ---- trinv residual: single barrier; rebalanced chain remainders ----
    {
      if (grp == 0) {
        trinv_steps(Wf, mdiag, 0, pass, lane, 6, 8);
        trinv_steps(Wf, mdiag, 6, pass, lane, 7, 8);
      } else if (grp == 1) {
        trinv_steps(Wf, mdiag, 1, pass, lane, 6, 8);
        trinv_steps(Wf, mdiag, 5, pass, lane, 6, 8);
      } else if (grp == 2) {
        trinv_steps(Wf, mdiag, 2, pass, lane, 6, 8);
        trinv_steps(Wf, mdiag, 4, pass, lane, 5, 8);
      } else {
        trinv_steps(Wf, mdiag, 3, pass, lane, 4, 8);
        // J=7 Linv solve (consumed by MC): diag-7 upper
        const int c16 = lane & 15;
        const int j16s = 4 * (lane >> 4) + pass;
        const int sh = lane & 48;
        float row[16];
        const float4* rp = (const float4*)(Wf + (112 + c16) * LDP + 112);
        float4 a0 = rp[0], a1 = rp[1], a2 = rp[2], a3 = rp[3];
        row[0]=a0.x; row[1]=a0.y; row[2]=a0.z; row[3]=a0.w;
        row[4]=a1.x; row[5]=a1.y; row[6]=a1.z; row[7]=a1.w;
        row[8]=a2.x; row[9]=a2.y; row[10]=a2.z; row[11]=a2.w;
        row[12]=a3.x; row[13]=a3.y; row[14]=a3.z; row[15]=a3.w;
        float s = (c16 == j16s) ? 1.0f : 0.0f;
        #pragma unroll
        for (int k = 0; k < 16; k++) {
          if (c16 == k) s *= mdiag[112 + k];
          float sk = __shfl(s, sh | k);
          if (c16 > k) s = fmaf(-row[k], sk, s);
        }
        if (c16 > j16s) Wf[(112 + j16s) * LDP + (112 + c16)] = s;
      }
      __syncthreads();
    }

    // ---- PHASE MC (single barrier): y=Mv (8 thr/row) + logdet;
    //      pack M^T -> Mtb ----
    {
      const int mrow = tid >> 3, kc = (tid & 7) * 16;
      float mtv[16];
      if (kc > mrow) {
        const float4* rp = (const float4*)(Wf + mrow * LDP + kc);
        float4 q0 = rp[0], q1 = rp[1], q2v = rp[2], q3 = rp[3];
        mtv[0]=q0.x; mtv[1]=q0.y; mtv[2]=q0.z; mtv[3]=q0.w;
        mtv[4]=q1.x; mtv[5]=q1.y; mtv[6]=q1.z; mtv[7]=q1.w;
        mtv[8]=q2v.x; mtv[9]=q2v.y; mtv[10]=q2v.z; mtv[11]=q2v.w;
        mtv[12]=q3.x; mtv[13]=q3.y; mtv[14]=q3.z; mtv[15]=q3.w;
      } else if (kc + 15 < mrow) {
        #pragma unroll
        for (int u = 0; u < 16; u++) mtv[u] = 0.0f;
      } else {
        #pragma unroll
        for (int u = 0; u < 16; u++) {
          const int k = kc + u;
          mtv[u] = (k > mrow) ? Wf[mrow * LDP + k]
                 : ((k == mrow) ? mdiag[mrow] : 0.0f);
        }
      }
      // y partial: row mrow, k in kc..kc+15 (plain GEMV, masked upper reads)
      {
        float p = 0.0f;
        #pragma unroll
        for (int u = 0; u < 16; u++) {
          const int k = kc + u;
          float val = (k < mrow) ? Wf[k * LDP + mrow]
                    : ((k == mrow) ? mdiag[mrow] : 0.0f);
          p = fmaf(val, vv[k], p);
        }
        p += __shfl_xor(p, 1);
        p += __shfl_xor(p, 2);
        p += __shfl_xor(p, 4);
        if ((tid & 7) == 0) {
          yv[mrow] = p;
          nllp -= __logf(mdiag[mrow]);
        }
      }
      unsigned short* mt = Mtb + mrow * LDB + kc;
      *(uint4*)(mt) = pack8(mtv);
      *(uint4*)(mt + 8) = pack8(mtv + 8);
      __syncthreads();
    }

    // ---- PHASE Pn (+fused A-build for step t+1): Sinv = M^T*M (lower);
    //      Pb = r2 I - r2^2 Sinv; m_post = z_t - r2*(Sinv v) -> mv;
    //      A(t+1) -> Ab2 ----
    {
      f32x4 acc[4];
      #pragma unroll
      for (int c = 0; c < 4; c++) acc[c] = (f32x4){0.0f, 0.0f, 0.0f, 0.0f};
      if (tid < DQ) nllp += 0.5f * yv[tid] * yv[tid];
      const int ctmax = rb - 4 * ch;
      if (ctmax >= 0) {
        for (int ks = (rb >> 1); ks < 4; ks++) {
          const int ko = 32 * ks + 8 * quad;
          bf16x8 a = *(const bf16x8*)(Mtb + (16 * rb + m16) * LDB + ko);
          #pragma unroll
          for (int ct = 0; ct < 4; ct++) {
            if (ct <= ctmax) {
              bf16x8 bb = *(const bf16x8*)(Mtb + (64 * ch + 16 * ct + m16) * LDB + ko);
              acc[ct] = __builtin_amdgcn_mfma_f32_16x16x32_bf16(a, bb, acc[ct], 0, 0, 0);
            }
          }
        }
      }
      const float nr22 = -r2 * r2;
      #pragma unroll
      for (int ct = 0; ct < 4; ct++) {
        if (ct <= ctmax) {
          const bool strict = (ct < ctmax);
          #pragma unroll
          for (int reg = 0; reg < 4; reg++) {
            const int rg = 16 * rb + 4 * quad + reg;
            const int cgl = 64 * ch + 16 * ct + m16;
            unsigned short hv = f2bf(nr22 * acc[ct][reg] + ((rg == cgl) ? r2 : 0.0f));
            Pb[rg * LDB + cgl] = hv;
            if (strict) Pb[cgl * LDB + rg] = hv;
          }
        }
      }
      if (tid < DQ) {
        const unsigned* mr = (const unsigned*)(Mtb + tid * LDB);
        float s = 0.0f;
        #pragma unroll 8
        for (int k2 = 0; k2 < 64; k2++) {
          unsigned p = mr[k2];
          s = fmaf(__uint_as_float(p << 16), yv[2 * k2], s);
          s = fmaf(__uint_as_float(p & 0xffff0000u), yv[2 * k2 + 1], s);
        }
        mv[tid] = zt[tid] - r2 * s;   // m_post = z - r2 * Sinv v
      }
      // ---- fused A-build for step t+1 (inputs only; independent) ----
      if (t < TQ - 1) {
        const float* mu_t = mu_seq + ((size_t)b * (TQ - 1) + t) * 4;
        const float* sg_t = sigma_seq + ((size_t)b * (TQ - 1) + t) * 16;
        const int unit = tid >> 2, q = tid & 3;
        const int r = unit >> 1, ss = unit & 1, tt = r >> 6, i = r & 63;
        float m0 = mu_t[0], m1 = mu_t[1], m2 = mu_t[2], m3 = mu_t[3];
        float dmx, dmy, c00, c01, c11;
        if (tt == 0 && ss == 0) {
          dmx = m0; dmy = m1;
          c00 = sg_t[0]; c01 = 0.5f * (sg_t[1] + sg_t[4]); c11 = sg_t[5];
        } else if (tt == 1 && ss == 1) {
          dmx = m2; dmy = m3;
          c00 = sg_t[10]; c01 = 0.5f * (sg_t[11] + sg_t[14]); c11 = sg_t[15];
        } else {
          dmx = 0.5f * (m0 + m2); dmy = 0.5f * (m1 + m3);
          float s00 = sg_t[0];
          float s02 = 0.5f * (sg_t[2] + sg_t[8]);
          float s22 = sg_t[10];
          float s01 = 0.5f * (sg_t[1] + sg_t[4]);
          float s03 = 0.5f * (sg_t[3] + sg_t[12]);
          float s21 = 0.5f * (sg_t[9] + sg_t[6]);
          float s23 = 0.5f * (sg_t[11] + sg_t[14]);
          float s11 = sg_t[5];
          float s13 = 0.5f * (sg_t[7] + sg_t[13]);
          float s33 = sg_t[15];
          c00 = 0.25f * (s00 + s02 + s02 + s22);
          c01 = 0.25f * (s01 + s03 + s21 + s23);
          c11 = 0.25f * (s11 + s13 + s13 + s33);
        }
        float D00 = 1.0001f + 2.0f * c00;
        float D01 = 2.0f * c01;
        float D11 = 1.0001f + 2.0f * c11;
        float det = D00 * D11 - D01 * D01;
        float dinv = 1.0f / det;
        float d00 = D11 * dinv, d01 = -D01 * dinv, d11 = D00 * dinv;
        float ldts = __logf(det);
        float cix = coords[2 * i], ciy = coords[2 * i + 1];
        const float* cj = coords + q * 32;
        float kv[16];
        float rsum = 0.0f;
        #pragma unroll
        for (int u = 0; u < 16; u++) {
          float dx = cix - cj[2 * u] - dmx;
          float dy = ciy - cj[2 * u + 1] - dmy;
          float qf = d00 * dx * dx + 2.0f * d01 * dx * dy + d11 * dy * dy;
          kv[u] = __expf(-0.5f * (qf + ldts));
          rsum += kv[u];
        }
        float rtot = rsum + __shfl_xor(rsum, 1);
        rtot += __shfl_xor(rtot, 2);
        float cv = (tt == 0) ? ((ss == 0) ? cpl00 : cpl01)
                             : ((ss == 0) ? cpl10 : cpl11);
        float norm = cv / fmaxf(rtot, 1e-6f);
        #pragma unroll
        for (int u = 0; u < 16; u++) kv[u] *= norm;
        if (ss == tt && ((i >> 4) == q)) kv[i & 15] += 1.0f - damping;
        unsigned short* arow = Ab2 + r * LDB + ss * 64 + q * 16;
        *(uint4*)(arow) = pack8(kv);
        *(uint4*)(arow + 8) = pack8(kv + 8);
      }
      __syncthreads();
    }
  }

  float total = block_reduce_sum(nllp, red);
  if (tid == 0)
    nll_out[b] = total + (float)TQ * 0.5f * (float)DQ * LOG2PI;
}

extern "C" __global__ void ide_finalize(const float* __restrict__ part,
                                        float* __restrict__ out) {
  if (threadIdx.x == 0) {
    float s = 0.0f;
    for (int i = 0; i < BQ; i++) s += part[i];
    out[0] = s * (1.0f / BQ);
  }
}

extern "C" void kernel_launch(void* const* d_in, const int* in_sizes, int n_in,
                              void* d_out, int out_size, void* d_ws, size_t ws_size,
                              hipStream_t stream) {
  (void)in_sizes; (void)n_in; (void)out_size; (void)ws_size;
  const float* z_seq        = (const float*)d_in[0];
  const float* site_lon     = (const float*)d_in[1];
  const float* site_lat     = (const float*)d_in[2];
  const float* mu_seq       = (const float*)d_in[3];
  const float* sigma_seq    = (const float*)d_in[4];
  const float* log_q        = (const float*)d_in[5];
  const float* log_r        = (const float*)d_in[6];
  const float* log_p0       = (const float*)d_in[7];
  const float* log_damp     = (const float*)d_in[8];
  const float* init_mean    = (const float*)d_in[9];
  const float* coupling_raw = (const float*)d_in[10];
  float* ws = (float*)d_ws;
  float* out = (float*)d_out;

  const size_t smem_bytes = (size_t)SMEM_FLOATS * sizeof(float);
  hipFuncSetAttribute((const void*)ide_kf_kernel,
                      hipFuncAttributeMaxDynamicSharedMemorySize,
                      (int)smem_bytes);

  hipLaunchKernelGGL(ide_kf_kernel, dim3(BQ), dim3(NTH), smem_bytes, stream,
                     z_seq, site_lon, site_lat, mu_seq, sigma_seq,
                     log_q, log_r, log_p0, log_damp, init_mean, coupling_raw,
                     ws);
  hipLaunchKernelGGL(ide_finalize, dim3(1), dim3(64), 0, stream, ws, out);
}

// Round 14
// 8269.000 us; speedup vs baseline: 1.0884x; 1.0884x over previous
//
#include <hip/hip_runtime.h>
#include <math.h>

// IDE state-space Kalman filter, MI355X (gfx950). Round 21:
// R19 EXACT (7806 us) + two LOCAL serial-chain cuts only (R20's trinv
// hoist into P1 reverted: at late kb the hoisted I-step outgrew the
// shrinking TRSM crew and became P1's phase max -> +15%, conflicts +37%):
// - MC y = M v at 8 threads/row (masked column reads, shfl_xor reduce,
//   seg0 writes yv + logdet). Chain 127 -> ~19.
// - Pn Sinv*v GEMV 2-way accumulator split (chain 128 -> 64, pure ILP).

#define SQ 64
#define DQ 128
#define TQ 128
#define BQ 16
#define LDP 132           // fp32 row stride
#define LDB 136           // bf16 row stride (16B-aligned rows, 2-way banks)
#define WFLOATS 17408     // W region: 69632 B (Tb + Ab2 bf16 when dead)
#define NTH 1024
#define LOG2PI 1.8378770664093454f

#define SMEM_FLOATS 35472

typedef __attribute__((ext_vector_type(8))) short bf16x8;
typedef __attribute__((ext_vector_type(4))) float f32x4;

__device__ __forceinline__ void lds_fence() {
  __asm__ volatile("s_waitcnt lgkmcnt(0)" ::: "memory");
}

__device__ __forceinline__ unsigned short f2bf(float f) {
  unsigned u = __float_as_uint(f);
  u += 0x7fffu + ((u >> 16) & 1u);
  return (unsigned short)(u >> 16);
}
__device__ __forceinline__ uint4 pack8(const float* v) {
  uint4 r;
  r.x = (unsigned)f2bf(v[0]) | ((unsigned)f2bf(v[1]) << 16);
  r.y = (unsigned)f2bf(v[2]) | ((unsigned)f2bf(v[3]) << 16);
  r.z = (unsigned)f2bf(v[4]) | ((unsigned)f2bf(v[5]) << 16);
  r.w = (unsigned)f2bf(v[6]) | ((unsigned)f2bf(v[7]) << 16);
  return r;
}

__device__ __forceinline__ float block_reduce_sum(float v, float* red) {
  #pragma unroll
  for (int off = 32; off > 0; off >>= 1) v += __shfl_down(v, off);
  const int tid = threadIdx.x;
  if ((tid & 63) == 0) red[tid >> 6] = v;
  __syncthreads();
  v = 0.0f;
  #pragma unroll
  for (int w = 0; w < NTH / 64; w++) v += red[w];
  __syncthreads();
  return v;
}

// 16x16 Cholesky, factor only (register/shfl resident on one wave).
__device__ __forceinline__ void chol16_f(float* __restrict__ Wf,
                                         float* __restrict__ mdiag,
                                         int b0, int lane) {
  float a[16];
  if (lane < 16) {
    const float4* rp = (const float4*)(Wf + (b0 + lane) * LDP + b0);
    float4 q0 = rp[0], q1 = rp[1], q2v = rp[2], q3 = rp[3];
    a[0]=q0.x; a[1]=q0.y; a[2]=q0.z; a[3]=q0.w;
    a[4]=q1.x; a[5]=q1.y; a[6]=q1.z; a[7]=q1.w;
    a[8]=q2v.x; a[9]=q2v.y; a[10]=q2v.z; a[11]=q2v.w;
    a[12]=q3.x; a[13]=q3.y; a[14]=q3.z; a[15]=q3.w;
  } else {
    #pragma unroll
    for (int i = 0; i < 16; i++) a[i] = 1.0f;
  }
  float myrinv = 1.0f;
  #pragma unroll
  for (int j = 0; j < 16; j++) {
    float dj = __shfl(a[j], j);
    float rinv = rsqrtf(dj);
    float lij = a[j] * rinv;
    a[j] = lij;
    if (lane == j) myrinv = rinv;
    #pragma unroll
    for (int k = j + 1; k < 16; k++) {
      float lkj = __shfl(lij, k);
      a[k] = fmaf(-lij, lkj, a[k]);
    }
  }
  if (lane < 16) {
    float4* rp = (float4*)(Wf + (b0 + lane) * LDP + b0);
    rp[0] = make_float4(a[0], a[1], a[2], a[3]);
    rp[1] = make_float4(a[4], a[5], a[6], a[7]);
    rp[2] = make_float4(a[8], a[9], a[10], a[11]);
    rp[3] = make_float4(a[12], a[13], a[14], a[15]);
    mdiag[b0 + lane] = myrinv;
  }
}

// One trinv chain: columns {4g+pass} of M(*,J). Linv_J (J=0..6) precomputed
// in chol P2 phases; do1 only for J=7 (consumed by MC). I<7 applies Linv_I
// via independent-shfl matmul; I=7 falls back to dependent substitution.
__device__ __forceinline__ void trinv_chain2(float* __restrict__ Wf,
                                             const float* __restrict__ mdiag,
                                             int J, int pass, int lane,
                                             bool do1) {
  const int c16 = lane & 15;
  const int j16 = 4 * (lane >> 4) + pass;
  const int sh = lane & 48;
  if (do1) {
    float row[16];
    const float4* rp = (const float4*)(Wf + (J * 16 + c16) * LDP + J * 16);
    float4 a0 = rp[0], a1 = rp[1], a2 = rp[2], a3 = rp[3];
    row[0]=a0.x; row[1]=a0.y; row[2]=a0.z; row[3]=a0.w;
    row[4]=a1.x; row[5]=a1.y; row[6]=a1.z; row[7]=a1.w;
    row[8]=a2.x; row[9]=a2.y; row[10]=a2.z; row[11]=a2.w;
    row[12]=a3.x; row[13]=a3.y; row[14]=a3.z; row[15]=a3.w;
    float s = (c16 == j16) ? 1.0f : 0.0f;
    #pragma unroll
    for (int k = 0; k < 16; k++) {
      if (c16 == k) s *= mdiag[J * 16 + k];
      float sk = __shfl(s, sh | k);
      if (c16 > k) s = fmaf(-row[k], sk, s);
    }
    if (c16 > j16) Wf[(J * 16 + j16) * LDP + (J * 16 + c16)] = s;
    lds_fence();
  }
  const float md = mdiag[J * 16 + j16];
  const float* Mrow = Wf + (J * 16 + j16) * LDP + J * 16;
  #pragma unroll 1
  for (int I = J + 1; I < 8; I++) {
    const float* Lrow = Wf + (I * 16 + c16) * LDP + J * 16;
    float g = 0.0f;
    // K = J: masked Linv_J read (hoisted upper + mdiag diagonal)
    #pragma unroll
    for (int c4 = 0; c4 < 4; c4++) {
      float4 lv = *(const float4*)&Lrow[c4 * 4];
      float4 mq = *(const float4*)&Mrow[c4 * 4];
      float w0 = (c4*4+0 > j16) ? mq.x : ((c4*4+0 == j16) ? md : 0.0f);
      float w1 = (c4*4+1 > j16) ? mq.y : ((c4*4+1 == j16) ? md : 0.0f);
      float w2 = (c4*4+2 > j16) ? mq.z : ((c4*4+2 == j16) ? md : 0.0f);
      float w3 = (c4*4+3 > j16) ? mq.w : ((c4*4+3 == j16) ? md : 0.0f);
      g = fmaf(lv.x, w0, g); g = fmaf(lv.y, w1, g);
      g = fmaf(lv.z, w2, g); g = fmaf(lv.w, w3, g);
    }
    for (int K = J + 1; K < I; K++) {
      const float* LK = Lrow + (K - J) * 16;
      const float* MK = Wf + (J * 16 + j16) * LDP + K * 16;
      #pragma unroll
      for (int c4 = 0; c4 < 4; c4++) {
        float4 lv = *(const float4*)&LK[c4 * 4];
        float4 mq = *(const float4*)&MK[c4 * 4];
        g = fmaf(lv.x, mq.x, g); g = fmaf(lv.y, mq.y, g);
        g = fmaf(lv.z, mq.z, g); g = fmaf(lv.w, mq.w, g);
      }
    }
    if (I < 7) {
      // apply hoisted Linv_I: independent shfls of original g (fast path)
      float s = mdiag[I * 16 + c16] * g;
      #pragma unroll
      for (int k = 0; k < 15; k++) {
        float gk = __shfl(g, sh | k);
        if (k < c16) {
          float u = Wf[(I * 16 + k) * LDP + I * 16 + c16];
          s = fmaf(u, gk, s);
        }
      }
      Wf[(J * 16 + j16) * LDP + (I * 16 + c16)] = -s;
    } else {
      // I = 7: Linv_7 unavailable; dependent forward substitution
      float row2[16];
      {
        const float4* rp2 = (const float4*)(Wf + (I * 16 + c16) * LDP + I * 16);
        float4 a0 = rp2[0], a1 = rp2[1], a2 = rp2[2], a3 = rp2[3];
        row2[0]=a0.x; row2[1]=a0.y; row2[2]=a0.z; row2[3]=a0.w;
        row2[4]=a1.x; row2[5]=a1.y; row2[6]=a1.z; row2[7]=a1.w;
        row2[8]=a2.x; row2[9]=a2.y; row2[10]=a2.z; row2[11]=a2.w;
        row2[12]=a3.x; row2[13]=a3.y; row2[14]=a3.z; row2[15]=a3.w;
      }
      float sv = g;
      #pragma unroll
      for (int k = 0; k < 16; k++) {
        if (c16 == k) sv *= mdiag[I * 16 + k];
        float sk = __shfl(sv, sh | k);
        if (c16 > k) sv = fmaf(-row2[k], sk, sv);
      }
      Wf[(J * 16 + j16) * LDP + (I * 16 + c16)] = -sv;
    }
    lds_fence();
  }
}

extern "C" __global__ __launch_bounds__(NTH, 4)
void ide_kf_kernel(const float* __restrict__ z_seq,
                   const float* __restrict__ site_lon,
                   const float* __restrict__ site_lat,
                   const float* __restrict__ mu_seq,
                   const float* __restrict__ sigma_seq,
                   const float* __restrict__ log_q,
                   const float* __restrict__ log_r,
                   const float* __restrict__ log_p0,
                   const float* __restrict__ log_damp,
                   const float* __restrict__ init_mean,
                   const float* __restrict__ coupling_raw,
                   float* __restrict__ ws) {
  extern __shared__ float smem[];
  float* Wf     = smem;                  // 17408 floats (fp32 chol space)
  float* B1f    = Wf + WFLOATS;          // 8704 floats (Mtb bf16 / Lhi)
  float* B2f    = B1f + 8704;            // 8704 floats (Pb bf16 / Llo)
  float* coords = B2f + 8704;            // 128
  float* mv     = coords + 128;          // 128 (posterior mean)
  float* vv     = mv + DQ;               // 128
  float* yv     = vv + DQ;               // 128
  float* mdiag  = yv + DQ;               // 128
  float* red    = mdiag + DQ;            // 16

  unsigned short* Tb  = (unsigned short*)Wf;            // bf16, stride LDB
  unsigned short* Ab2 = (unsigned short*)Wf + 17408;    // A bf16 (Wf upper)
  unsigned short* Mtb = (unsigned short*)B1f;           // M^T bf16
  unsigned short* Pb  = (unsigned short*)B2f;           // P bf16 (symmetric)
  unsigned short* Lhi = (unsigned short*)B1f;           // chol L hi (Mtb dead)
  unsigned short* Llo = (unsigned short*)B2f;           // chol L lo (Pb dead)

  const int tid = threadIdx.x;
  const int lane = tid & 63;
  const int wave = tid >> 6;
  const int rb = wave >> 1, ch = wave & 1;
  const int m16 = lane & 15, quad = lane >> 4;
  const int grp = wave >> 2, pass = wave & 3;
  const int b = blockIdx.x;
  float* nll_out = ws;

  const float r2 = __expf(2.0f * log_r[0]);
  const float q2 = __expf(2.0f * log_q[0]);
  const float p0sq = __expf(2.0f * log_p0[0]);
  const float damping = __expf(log_damp[0]);
  const float cpl00 = 1.0f + 0.25f * tanhf(coupling_raw[0]);
  const float cpl01 = 0.25f * tanhf(coupling_raw[1]);
  const float cpl10 = 0.25f * tanhf(coupling_raw[2]);
  const float cpl11 = 1.0f + 0.25f * tanhf(coupling_raw[3]);

  // ---- lon/lat projection ----
  float myLon = (tid < SQ) ? site_lon[tid] : 0.0f;
  float myLat = (tid < SQ) ? site_lat[tid] : 0.0f;
  float lat0 = block_reduce_sum(myLat, red) * (1.0f / 64.0f);
  float lon0 = block_reduce_sum(myLon, red) * (1.0f / 64.0f);
  if (tid < SQ) {
    const float km = 111.32f;
    float cs = cosf(lat0 * 0.017453292519943295f);
    coords[2 * tid]     = (myLon - lon0) * (km * cs);
    coords[2 * tid + 1] = (myLat - lat0) * km;
  }
  __syncthreads();
  float dsum = 0.0f, dcnt = 0.0f;
  for (int idx = tid; idx < SQ * SQ; idx += NTH) {
    int i = idx >> 6, j = idx & 63;
    float dx = coords[2 * i] - coords[2 * j];
    float dy = coords[2 * i + 1] - coords[2 * j + 1];
    float d = sqrtf(dx * dx + dy * dy + 1e-12f);
    dsum += d;
    if (d > 1e-6f) dcnt += 1.0f;
  }
  dsum = block_reduce_sum(dsum, red);
  dcnt = block_reduce_sum(dcnt, red);
  float scale = dsum / fmaxf(dcnt, 1.0f);
  float sdiv = 1.0f / fmaxf(scale, 1e-6f);
  if (tid < SQ) { coords[2 * tid] *= sdiv; coords[2 * tid + 1] *= sdiv; }

  // ---- init: Wf = (p0sq+r2) I, mv = init_mean ----
  for (int e = tid; e < WFLOATS / 4; e += NTH)
    ((float4*)Wf)[e] = make_float4(0.0f, 0.0f, 0.0f, 0.0f);
  for (int e = tid; e < 8704 / 4; e += NTH)
    ((float4*)B2f)[e] = make_float4(0.0f, 0.0f, 0.0f, 0.0f);
  __syncthreads();
  if (tid < DQ) {
    Wf[tid * LDP + tid] = p0sq + r2;
    mv[tid] = init_mean[tid];
  }
  __syncthreads();

  float nllp = 0.0f;

  #pragma unroll 1
  for (int t = 0; t < TQ; t++) {
    const float* zt = z_seq + ((size_t)b * TQ + t) * DQ;

    if (t > 0) {
      // ---- PHASE T: mfma T = A*P -> Tb (single barrier) ----
      {
        f32x4 acc[4];
        #pragma unroll
        for (int c = 0; c < 4; c++) acc[c] = (f32x4){0.0f, 0.0f, 0.0f, 0.0f};
        #pragma unroll
        for (int ks = 0; ks < 4; ks++) {
          const int ko = 32 * ks + 8 * quad;
          bf16x8 a = *(const bf16x8*)(Ab2 + (16 * rb + m16) * LDB + ko);
          #pragma unroll
          for (int ct = 0; ct < 4; ct++) {
            bf16x8 bb = *(const bf16x8*)(Pb + (64 * ch + 16 * ct + m16) * LDB + ko);
            acc[ct] = __builtin_amdgcn_mfma_f32_16x16x32_bf16(a, bb, acc[ct], 0, 0, 0);
          }
        }
        #pragma unroll
        for (int ct = 0; ct < 4; ct++)
          #pragma unroll
          for (int reg = 0; reg < 4; reg++)
            Tb[(16 * rb + 4 * quad + reg) * LDB + 64 * ch + 16 * ct + m16] =
                f2bf(acc[ct][reg]);
        __syncthreads();
      }

      // ---- PHASE P': part1: Sm MFMA + m-GEMV (idle waves 1,3);
      //      midbar; part2: fp32 Wf + wave0 chol16_f(0) + vv ----
      {
        const int ctmax = rb - 4 * ch;
        f32x4 acc[4];
        #pragma unroll
        for (int c = 0; c < 4; c++) acc[c] = (f32x4){0.0f, 0.0f, 0.0f, 0.0f};
        const bool gemv_wave = (wave == 1 || wave == 3);
        const int grow = (wave == 1) ? lane : 64 + lane;
        float newm = 0.0f;
        if (ctmax >= 0) {
          #pragma unroll
          for (int ks = 0; ks < 4; ks++) {
            const int ko = 32 * ks + 8 * quad;
            bf16x8 a = *(const bf16x8*)(Tb + (16 * rb + m16) * LDB + ko);
            #pragma unroll
            for (int ct = 0; ct < 4; ct++) {
              if (ct <= ctmax) {
                bf16x8 bb = *(const bf16x8*)(Ab2 + (64 * ch + 16 * ct + m16) * LDB + ko);
                acc[ct] = __builtin_amdgcn_mfma_f32_16x16x32_bf16(a, bb, acc[ct], 0, 0, 0);
              }
            }
          }
        } else if (gemv_wave) {
          const unsigned* ar = (const unsigned*)(Ab2 + grow * LDB);
          #pragma unroll 8
          for (int k2 = 0; k2 < 64; k2++) {
            unsigned p = ar[k2];
            newm = fmaf(__uint_as_float(p << 16), mv[2 * k2], newm);
            newm = fmaf(__uint_as_float(p & 0xffff0000u), mv[2 * k2 + 1], newm);
          }
        }
        __syncthreads();   // Tb/Ab2 reads done
        if (ctmax >= 0) {
          #pragma unroll
          for (int ct = 0; ct < 4; ct++) {
            if (ct <= ctmax) {
              #pragma unroll
              for (int reg = 0; reg < 4; reg++) {
                const int rg = 16 * rb + 4 * quad + reg;
                const int cgl = 64 * ch + 16 * ct + m16;
                Wf[rg * LDP + cgl] = acc[ct][reg] + ((rg == cgl) ? (q2 + r2) : 0.0f);
              }
            }
          }
        }
        if (gemv_wave) vv[grow] = zt[grow] - newm;
        if (wave == 0) {
          lds_fence();
          chol16_f(Wf, mdiag, 0, lane);
        }
        __syncthreads();
      }
    }

    if (t == 0) {
      // ---- K0 (t=0 only): wave0 chol diag0 ; vv ----
      if (tid < 64) {
        chol16_f(Wf, mdiag, 0, lane);
      } else if (tid < 192) {
        const int i = tid - 64;
        vv[i] = zt[i] - mv[i];
      }
      __syncthreads();
    }

    // ---- chol: LEFT-LOOKING, split-bf16 MFMA column updates ----
    #pragma unroll 1
    for (int kb = 0; kb < 7; kb++) {
      const int b0k = kb * 16, base = b0k + 16, nbelow = DQ - base;
      // P1: TRSM rows base..127 vs diag kb + pack hi/lo + zero next slot
      if (tid < nbelow) {
        const int r = base + tid;
        float* wr = Wf + r * LDP + b0k;
        float w[16];
        #pragma unroll
        for (int u4 = 0; u4 < 4; u4++) {
          float4 w4 = *(const float4*)&wr[u4 * 4];
          w[u4*4] = w4.x; w[u4*4+1] = w4.y; w[u4*4+2] = w4.z; w[u4*4+3] = w4.w;
        }
        #pragma unroll
        for (int j = 0; j < 16; j++) {
          float s = w[j];
          #pragma unroll
          for (int l = 0; l < 16; l++) {
            if (l < j) s = fmaf(-w[l], Wf[(b0k + j) * LDP + b0k + l], s);
          }
          w[j] = s * mdiag[b0k + j];
        }
        #pragma unroll
        for (int u4 = 0; u4 < 4; u4++)
          *(float4*)&wr[u4 * 4] =
              make_float4(w[u4*4], w[u4*4+1], w[u4*4+2], w[u4*4+3]);
        // split-bf16 pack: w = hi + lo
        unsigned short hs[16]; float lo[16];
        #pragma unroll
        for (int u = 0; u < 16; u++) {
          hs[u] = f2bf(w[u]);
          lo[u] = w[u] - __uint_as_float(((unsigned)hs[u]) << 16);
        }
        uint4 h0, h1;
        h0.x = hs[0] | ((unsigned)hs[1] << 16);   h0.y = hs[2] | ((unsigned)hs[3] << 16);
        h0.z = hs[4] | ((unsigned)hs[5] << 16);   h0.w = hs[6] | ((unsigned)hs[7] << 16);
        h1.x = hs[8] | ((unsigned)hs[9] << 16);   h1.y = hs[10] | ((unsigned)hs[11] << 16);
        h1.z = hs[12] | ((unsigned)hs[13] << 16); h1.w = hs[14] | ((unsigned)hs[15] << 16);
        unsigned short* hr = Lhi + r * LDB + b0k;
        unsigned short* lr = Llo + r * LDB + b0k;
        *(uint4*)(hr) = h0; *(uint4*)(hr + 8) = h1;
        *(uint4*)(lr) = pack8(lo); *(uint4*)(lr + 8) = pack8(lo + 8);
        // zero next panel's column slot (odd-K chunk overshoot reads zeros)
        const uint4 z4 = make_uint4(0u, 0u, 0u, 0u);
        *(uint4*)(hr + 16) = z4; *(uint4*)(hr + 24) = z4;
        *(uint4*)(lr + 16) = z4; *(uint4*)(lr + 24) = z4;
      }
      __syncthreads();
      // P2: U(kb+1) tiles; wave0 diag + chol16; waves 8-11: Linv_kb solve
      if (wave <= 6 - kb) {
        const int bi = kb + 1 + wave;
        const int nch = (kb + 2) >> 1;   // ceil(16(kb+1)/32)
        f32x4 acc = (f32x4){0.0f, 0.0f, 0.0f, 0.0f};
        for (int c = 0; c < nch; c++) {
          const int ko = 32 * c + 8 * quad;
          bf16x8 ahi = *(const bf16x8*)(Lhi + (16 * bi + m16) * LDB + ko);
          bf16x8 alo = *(const bf16x8*)(Llo + (16 * bi + m16) * LDB + ko);
          bf16x8 bhi = *(const bf16x8*)(Lhi + (base + m16) * LDB + ko);
          bf16x8 blo = *(const bf16x8*)(Llo + (base + m16) * LDB + ko);
          acc = __builtin_amdgcn_mfma_f32_16x16x32_bf16(ahi, bhi, acc, 0, 0, 0);
          acc = __builtin_amdgcn_mfma_f32_16x16x32_bf16(ahi, blo, acc, 0, 0, 0);
          acc = __builtin_amdgcn_mfma_f32_16x16x32_bf16(alo, bhi, acc, 0, 0, 0);
        }
        #pragma unroll
        for (int reg = 0; reg < 4; reg++)
          Wf[(16 * bi + 4 * quad + reg) * LDP + base + m16] -= acc[reg];
        if (wave == 0) {
          lds_fence();
          chol16_f(Wf, mdiag, base, lane);
        }
      } else if (wave >= 8 && wave <= 11) {
        // Linv_kb column solve (pass = wave-8) -> diag-kb upper.
        const int c16 = lane & 15;
        const int j16s = 4 * (lane >> 4) + (wave - 8);
        const int sh = lane & 48;
        float row[16];
        const float4* rp = (const float4*)(Wf + (b0k + c16) * LDP + b0k);
        float4 a0 = rp[0], a1 = rp[1], a2 = rp[2], a3 = rp[3];
        row[0]=a0.x; row[1]=a0.y; row[2]=a0.z; row[3]=a0.w;
        row[4]=a1.x; row[5]=a1.y; row[6]=a1.z; row[7]=a1.w;
        row[8]=a2.x; row[9]=a2.y; row[10]=a2.z; row[11]=a2.w;
        row[12]=a3.x; row[13]=a3.y; row[14]=a3.z; row[15]=a3.w;
        float s = (c16 == j16s) ? 1.0f : 0.0f;
        #pragma unroll
        for (int k = 0; k < 16; k++) {
          if (c16 == k) s *= mdiag[b0k + k];
          float sk = __shfl(s, sh | k);
          if (c16 > k) s = fmaf(-row[k], sk, s);
        }
        if (c16 > j16s) Wf[(b0k + j16s) * LDP + (b0k + c16)] = s;
      }
      __syncthreads();
    }

    // ---- trinv: single barrier; Linv pre-hoisted (J=0..6); fast I-apply ----
    {
      #pragma unroll 1
      for (int cc = 0; cc < 2; cc++) {
        const int J = cc ? (7 - grp) : grp;
        trinv_chain2(Wf, mdiag, J, pass, lane, cc == 1 && grp == 0);
      }
      __syncthreads();
    }

    // ---- PHASE MC (single barrier): y=Mv (8 thr/row) + logdet;
    //      pack M^T -> Mtb ----
    {
      const int mrow = tid >> 3, kc = (tid & 7) * 16;
      float mtv[16];
      if (kc > mrow) {
        const float4* rp = (const float4*)(Wf + mrow * LDP + kc);
        float4 q0 = rp[0], q1 = rp[1], q2v = rp[2], q3 = rp[3];
        mtv[0]=q0.x; mtv[1]=q0.y; mtv[2]=q0.z; mtv[3]=q0.w;
        mtv[4]=q1.x; mtv[5]=q1.y; mtv[6]=q1.z; mtv[7]=q1.w;
        mtv[8]=q2v.x; mtv[9]=q2v.y; mtv[10]=q2v.z; mtv[11]=q2v.w;
        mtv[12]=q3.x; mtv[13]=q3.y; mtv[14]=q3.z; mtv[15]=q3.w;
      } else if (kc + 15 < mrow) {
        #pragma unroll
        for (int u = 0; u < 16; u++) mtv[u] = 0.0f;
      } else {
        #pragma unroll
        for (int u = 0; u < 16; u++) {
          const int k = kc + u;
          mtv[u] = (k > mrow) ? Wf[mrow * LDP + k]
                 : ((k == mrow) ? mdiag[mrow] : 0.0f);
        }
      }
      // y partial: row mrow, k in kc..kc+15 (plain GEMV, masked reads)
      {
        float p = 0.0f;
        #pragma unroll
        for (int u = 0; u < 16; u++) {
          const int k = kc + u;
          float val = (k < mrow) ? Wf[k * LDP + mrow]
                    : ((k == mrow) ? mdiag[mrow] : 0.0f);
          p = fmaf(val, vv[k], p);
        }
        p += __shfl_xor(p, 1);
        p += __shfl_xor(p, 2);
        p += __shfl_xor(p, 4);
        if ((tid & 7) == 0) {
          yv[mrow] = p;
          nllp -= __logf(mdiag[mrow]);
        }
      }
      unsigned short* mt = Mtb + mrow * LDB + kc;
      *(uint4*)(mt) = pack8(mtv);
      *(uint4*)(mt + 8) = pack8(mtv + 8);
      __syncthreads();
    }

    // ---- PHASE Pn (+fused A-build for step t+1): Sinv = M^T*M (lower);
    //      Pb = r2 I - r2^2 Sinv; m_post = z_t - r2*(Sinv v) -> mv;
    //      A(t+1) -> Ab2 ----
    {
      f32x4 acc[4];
      #pragma unroll
      for (int c = 0; c < 4; c++) acc[c] = (f32x4){0.0f, 0.0f, 0.0f, 0.0f};
      if (tid < DQ) nllp += 0.5f * yv[tid] * yv[tid];
      const int ctmax = rb - 4 * ch;
      if (ctmax >= 0) {
        for (int ks = (rb >> 1); ks < 4; ks++) {
          const int ko = 32 * ks + 8 * quad;
          bf16x8 a = *(const bf16x8*)(Mtb + (16 * rb + m16) * LDB + ko);
          #pragma unroll
          for (int ct = 0; ct < 4; ct++) {
            if (ct <= ctmax) {
              bf16x8 bb = *(const bf16x8*)(Mtb + (64 * ch + 16 * ct + m16) * LDB + ko);
              acc[ct] = __builtin_amdgcn_mfma_f32_16x16x32_bf16(a, bb, acc[ct], 0, 0, 0);
            }
          }
        }
      }
      const float nr22 = -r2 * r2;
      #pragma unroll
      for (int ct = 0; ct < 4; ct++) {
        if (ct <= ctmax) {
          const bool strict = (ct < ctmax);
          #pragma unroll
          for (int reg = 0; reg < 4; reg++) {
            const int rg = 16 * rb + 4 * quad + reg;
            const int cgl = 64 * ch + 16 * ct + m16;
            unsigned short hv = f2bf(nr22 * acc[ct][reg] + ((rg == cgl) ? r2 : 0.0f));
            Pb[rg * LDB + cgl] = hv;
            if (strict) Pb[cgl * LDB + rg] = hv;
          }
        }
      }
      if (tid < DQ) {
        const unsigned* mr = (const unsigned*)(Mtb + tid * LDB);
        float sa = 0.0f, sb = 0.0f;
        #pragma unroll 8
        for (int k2 = 0; k2 < 64; k2 += 2) {
          unsigned p0 = mr[k2], p1 = mr[k2 + 1];
          sa = fmaf(__uint_as_float(p0 << 16), yv[2 * k2], sa);
          sa = fmaf(__uint_as_float(p0 & 0xffff0000u), yv[2 * k2 + 1], sa);
          sb = fmaf(__uint_as_float(p1 << 16), yv[2 * k2 + 2], sb);
          sb = fmaf(__uint_as_float(p1 & 0xffff0000u), yv[2 * k2 + 3], sb);
        }
        mv[tid] = zt[tid] - r2 * (sa + sb);   // m_post = z - r2 * Sinv v
      }
      // ---- fused A-build for step t+1 (inputs only; independent) ----
      if (t < TQ - 1) {
        const float* mu_t = mu_seq + ((size_t)b * (TQ - 1) + t) * 4;
        const float* sg_t = sigma_seq + ((size_t)b * (TQ - 1) + t) * 16;
        const int unit = tid >> 2, q = tid & 3;
        const int r = unit >> 1, ss = unit & 1, tt = r >> 6, i = r & 63;
        float m0 = mu_t[0], m1 = mu_t[1], m2 = mu_t[2], m3 = mu_t[3];
        float dmx, dmy, c00, c01, c11;
        if (tt == 0 && ss == 0) {
          dmx = m0; dmy = m1;
          c00 = sg_t[0]; c01 = 0.5f * (sg_t[1] + sg_t[4]); c11 = sg_t[5];
        } else if (tt == 1 && ss == 1) {
          dmx = m2; dmy = m3;
          c00 = sg_t[10]; c01 = 0.5f * (sg_t[11] + sg_t[14]); c11 = sg_t[15];
        } else {
          dmx = 0.5f * (m0 + m2); dmy = 0.5f * (m1 + m3);
          float s00 = sg_t[0];
          float s02 = 0.5f * (sg_t[2] + sg_t[8]);
          float s22 = sg_t[10];
          float s01 = 0.5f * (sg_t[1] + sg_t[4]);
          float s03 = 0.5f * (sg_t[3] + sg_t[12]);
          float s21 = 0.5f * (sg_t[9] + sg_t[6]);
          float s23 = 0.5f * (sg_t[11] + sg_t[14]);
          float s11 = sg_t[5];
          float s13 = 0.5f * (sg_t[7] + sg_t[13]);
          float s33 = sg_t[15];
          c00 = 0.25f * (s00 + s02 + s02 + s22);
          c01 = 0.25f * (s01 + s03 + s21 + s23);
          c11 = 0.25f * (s11 + s13 + s13 + s33);
        }
        float D00 = 1.0001f + 2.0f * c00;
        float D01 = 2.0f * c01;
        float D11 = 1.0001f + 2.0f * c11;
        float det = D00 * D11 - D01 * D01;
        float dinv = 1.0f / det;
        float d00 = D11 * dinv, d01 = -D01 * dinv, d11 = D00 * dinv;
        float ldts = __logf(det);
        float cix = coords[2 * i], ciy = coords[2 * i + 1];
        const float* cj = coords + q * 32;
        float kv[16];
        float rsum = 0.0f;
        #pragma unroll
        for (int u = 0; u < 16; u++) {
          float dx = cix - cj[2 * u] - dmx;
          float dy = ciy - cj[2 * u + 1] - dmy;
          float qf = d00 * dx * dx + 2.0f * d01 * dx * dy + d11 * dy * dy;
          kv[u] = __expf(-0.5f * (qf + ldts));
          rsum += kv[u];
        }
        float rtot = rsum + __shfl_xor(rsum, 1);
        rtot += __shfl_xor(rtot, 2);
        float cv = (tt == 0) ? ((ss == 0) ? cpl00 : cpl01)
                             : ((ss == 0) ? cpl10 : cpl11);
        float norm = cv / fmaxf(rtot, 1e-6f);
        #pragma unroll
        for (int u = 0; u < 16; u++) kv[u] *= norm;
        if (ss == tt && ((i >> 4) == q)) kv[i & 15] += 1.0f - damping;
        unsigned short* arow = Ab2 + r * LDB + ss * 64 + q * 16;
        *(uint4*)(arow) = pack8(kv);
        *(uint4*)(arow + 8) = pack8(kv + 8);
      }
      __syncthreads();
    }
  }

  float total = block_reduce_sum(nllp, red);
  if (tid == 0)
    nll_out[b] = total + (float)TQ * 0.5f * (float)DQ * LOG2PI;
}

extern "C" __global__ void ide_finalize(const float* __restrict__ part,
                                        float* __restrict__ out) {
  if (threadIdx.x == 0) {
    float s = 0.0f;
    for (int i = 0; i < BQ; i++) s += part[i];
    out[0] = s * (1.0f / BQ);
  }
}

extern "C" void kernel_launch(void* const* d_in, const int* in_sizes, int n_in,
                              void* d_out, int out_size, void* d_ws, size_t ws_size,
                              hipStream_t stream) {
  (void)in_sizes; (void)n_in; (void)out_size; (void)ws_size;
  const float* z_seq        = (const float*)d_in[0];
  const float* site_lon     = (const float*)d_in[1];
  const float* site_lat     = (const float*)d_in[2];
  const float* mu_seq       = (const float*)d_in[3];
  const float* sigma_seq    = (const float*)d_in[4];
  const float* log_q        = (const float*)d_in[5];
  const float* log_r        = (const float*)d_in[6];
  const float* log_p0       = (const float*)d_in[7];
  const float* log_damp     = (const float*)d_in[8];
  const float* init_mean    = (const float*)d_in[9];
  const float* coupling_raw = (const float*)d_in[10];
  float* ws = (float*)d_ws;
  float* out = (float*)d_out;

  const size_t smem_bytes = (size_t)SMEM_FLOATS * sizeof(float);
  hipFuncSetAttribute((const void*)ide_kf_kernel,
                      hipFuncAttributeMaxDynamicSharedMemorySize,
                      (int)smem_bytes);

  hipLaunchKernelGGL(ide_kf_kernel, dim3(BQ), dim3(NTH), smem_bytes, stream,
                     z_seq, site_lon, site_lat, mu_seq, sigma_seq,
                     log_q, log_r, log_p0, log_damp, init_mean, coupling_raw,
                     ws);
  hipLaunchKernelGGL(ide_finalize, dim3(1), dim3(64), 0, stream, ws, out);
}

// Round 15
// 7806.981 us; speedup vs baseline: 1.1528x; 1.0592x over previous
//
#include <hip/hip_runtime.h>
#include <math.h>

// IDE state-space Kalman filter, MI355X (gfx950). Round 22 = R19 EXACT
// (7806 us, session best). R20 (trinv hoist into P1) and R21 (MC y-GEMV
// 8-thr/row + Pn split) both regressed: the hoist outgrew late-kb P1
// phase maxima (+15%); the transposed y-GEMV reads added 37% bank
// conflicts (+6%). R19's schedule is a local optimum of this family:
// - left-looking chol, split-bf16 MFMA column updates (R16)
// - Linv solves hoisted into chol P2 idle waves (waves 8-11)
// - trinv fast I-apply via independent shfls of hoisted Linv_I
// - algebra: no Phase Y, Sinv = M^T M, P = r2 I - r2^2 Sinv,
//   m_post = z - r2 Sinv v; A-build fused into Pn.

#define SQ 64
#define DQ 128
#define TQ 128
#define BQ 16
#define LDP 132           // fp32 row stride
#define LDB 136           // bf16 row stride (16B-aligned rows, 2-way banks)
#define WFLOATS 17408     // W region: 69632 B (Tb + Ab2 bf16 when dead)
#define NTH 1024
#define LOG2PI 1.8378770664093454f

#define SMEM_FLOATS 35472

typedef __attribute__((ext_vector_type(8))) short bf16x8;
typedef __attribute__((ext_vector_type(4))) float f32x4;

__device__ __forceinline__ void lds_fence() {
  __asm__ volatile("s_waitcnt lgkmcnt(0)" ::: "memory");
}

__device__ __forceinline__ unsigned short f2bf(float f) {
  unsigned u = __float_as_uint(f);
  u += 0x7fffu + ((u >> 16) & 1u);
  return (unsigned short)(u >> 16);
}
__device__ __forceinline__ uint4 pack8(const float* v) {
  uint4 r;
  r.x = (unsigned)f2bf(v[0]) | ((unsigned)f2bf(v[1]) << 16);
  r.y = (unsigned)f2bf(v[2]) | ((unsigned)f2bf(v[3]) << 16);
  r.z = (unsigned)f2bf(v[4]) | ((unsigned)f2bf(v[5]) << 16);
  r.w = (unsigned)f2bf(v[6]) | ((unsigned)f2bf(v[7]) << 16);
  return r;
}

__device__ __forceinline__ float block_reduce_sum(float v, float* red) {
  #pragma unroll
  for (int off = 32; off > 0; off >>= 1) v += __shfl_down(v, off);
  const int tid = threadIdx.x;
  if ((tid & 63) == 0) red[tid >> 6] = v;
  __syncthreads();
  v = 0.0f;
  #pragma unroll
  for (int w = 0; w < NTH / 64; w++) v += red[w];
  __syncthreads();
  return v;
}

// 16x16 Cholesky, factor only (register/shfl resident on one wave).
__device__ __forceinline__ void chol16_f(float* __restrict__ Wf,
                                         float* __restrict__ mdiag,
                                         int b0, int lane) {
  float a[16];
  if (lane < 16) {
    const float4* rp = (const float4*)(Wf + (b0 + lane) * LDP + b0);
    float4 q0 = rp[0], q1 = rp[1], q2v = rp[2], q3 = rp[3];
    a[0]=q0.x; a[1]=q0.y; a[2]=q0.z; a[3]=q0.w;
    a[4]=q1.x; a[5]=q1.y; a[6]=q1.z; a[7]=q1.w;
    a[8]=q2v.x; a[9]=q2v.y; a[10]=q2v.z; a[11]=q2v.w;
    a[12]=q3.x; a[13]=q3.y; a[14]=q3.z; a[15]=q3.w;
  } else {
    #pragma unroll
    for (int i = 0; i < 16; i++) a[i] = 1.0f;
  }
  float myrinv = 1.0f;
  #pragma unroll
  for (int j = 0; j < 16; j++) {
    float dj = __shfl(a[j], j);
    float rinv = rsqrtf(dj);
    float lij = a[j] * rinv;
    a[j] = lij;
    if (lane == j) myrinv = rinv;
    #pragma unroll
    for (int k = j + 1; k < 16; k++) {
      float lkj = __shfl(lij, k);
      a[k] = fmaf(-lij, lkj, a[k]);
    }
  }
  if (lane < 16) {
    float4* rp = (float4*)(Wf + (b0 + lane) * LDP + b0);
    rp[0] = make_float4(a[0], a[1], a[2], a[3]);
    rp[1] = make_float4(a[4], a[5], a[6], a[7]);
    rp[2] = make_float4(a[8], a[9], a[10], a[11]);
    rp[3] = make_float4(a[12], a[13], a[14], a[15]);
    mdiag[b0 + lane] = myrinv;
  }
}

// One trinv chain: columns {4g+pass} of M(*,J). Linv_J (J=0..6) precomputed
// in chol P2 phases; do1 only for J=7 (consumed by MC). I<7 applies Linv_I
// via independent-shfl matmul; I=7 falls back to dependent substitution.
__device__ __forceinline__ void trinv_chain2(float* __restrict__ Wf,
                                             const float* __restrict__ mdiag,
                                             int J, int pass, int lane,
                                             bool do1) {
  const int c16 = lane & 15;
  const int j16 = 4 * (lane >> 4) + pass;
  const int sh = lane & 48;
  if (do1) {
    float row[16];
    const float4* rp = (const float4*)(Wf + (J * 16 + c16) * LDP + J * 16);
    float4 a0 = rp[0], a1 = rp[1], a2 = rp[2], a3 = rp[3];
    row[0]=a0.x; row[1]=a0.y; row[2]=a0.z; row[3]=a0.w;
    row[4]=a1.x; row[5]=a1.y; row[6]=a1.z; row[7]=a1.w;
    row[8]=a2.x; row[9]=a2.y; row[10]=a2.z; row[11]=a2.w;
    row[12]=a3.x; row[13]=a3.y; row[14]=a3.z; row[15]=a3.w;
    float s = (c16 == j16) ? 1.0f : 0.0f;
    #pragma unroll
    for (int k = 0; k < 16; k++) {
      if (c16 == k) s *= mdiag[J * 16 + k];
      float sk = __shfl(s, sh | k);
      if (c16 > k) s = fmaf(-row[k], sk, s);
    }
    if (c16 > j16) Wf[(J * 16 + j16) * LDP + (J * 16 + c16)] = s;
    lds_fence();
  }
  const float md = mdiag[J * 16 + j16];
  const float* Mrow = Wf + (J * 16 + j16) * LDP + J * 16;
  #pragma unroll 1
  for (int I = J + 1; I < 8; I++) {
    const float* Lrow = Wf + (I * 16 + c16) * LDP + J * 16;
    float g = 0.0f;
    // K = J: masked Linv_J read (hoisted upper + mdiag diagonal)
    #pragma unroll
    for (int c4 = 0; c4 < 4; c4++) {
      float4 lv = *(const float4*)&Lrow[c4 * 4];
      float4 mq = *(const float4*)&Mrow[c4 * 4];
      float w0 = (c4*4+0 > j16) ? mq.x : ((c4*4+0 == j16) ? md : 0.0f);
      float w1 = (c4*4+1 > j16) ? mq.y : ((c4*4+1 == j16) ? md : 0.0f);
      float w2 = (c4*4+2 > j16) ? mq.z : ((c4*4+2 == j16) ? md : 0.0f);
      float w3 = (c4*4+3 > j16) ? mq.w : ((c4*4+3 == j16) ? md : 0.0f);
      g = fmaf(lv.x, w0, g); g = fmaf(lv.y, w1, g);
      g = fmaf(lv.z, w2, g); g = fmaf(lv.w, w3, g);
    }
    for (int K = J + 1; K < I; K++) {
      const float* LK = Lrow + (K - J) * 16;
      const float* MK = Wf + (J * 16 + j16) * LDP + K * 16;
      #pragma unroll
      for (int c4 = 0; c4 < 4; c4++) {
        float4 lv = *(const float4*)&LK[c4 * 4];
        float4 mq = *(const float4*)&MK[c4 * 4];
        g = fmaf(lv.x, mq.x, g); g = fmaf(lv.y, mq.y, g);
        g = fmaf(lv.z, mq.z, g); g = fmaf(lv.w, mq.w, g);
      }
    }
    if (I < 7) {
      // apply hoisted Linv_I: independent shfls of original g (fast path)
      float s = mdiag[I * 16 + c16] * g;
      #pragma unroll
      for (int k = 0; k < 15; k++) {
        float gk = __shfl(g, sh | k);
        if (k < c16) {
          float u = Wf[(I * 16 + k) * LDP + I * 16 + c16];
          s = fmaf(u, gk, s);
        }
      }
      Wf[(J * 16 + j16) * LDP + (I * 16 + c16)] = -s;
    } else {
      // I = 7: Linv_7 unavailable; dependent forward substitution
      float row2[16];
      {
        const float4* rp2 = (const float4*)(Wf + (I * 16 + c16) * LDP + I * 16);
        float4 a0 = rp2[0], a1 = rp2[1], a2 = rp2[2], a3 = rp2[3];
        row2[0]=a0.x; row2[1]=a0.y; row2[2]=a0.z; row2[3]=a0.w;
        row2[4]=a1.x; row2[5]=a1.y; row2[6]=a1.z; row2[7]=a1.w;
        row2[8]=a2.x; row2[9]=a2.y; row2[10]=a2.z; row2[11]=a2.w;
        row2[12]=a3.x; row2[13]=a3.y; row2[14]=a3.z; row2[15]=a3.w;
      }
      float sv = g;
      #pragma unroll
      for (int k = 0; k < 16; k++) {
        if (c16 == k) sv *= mdiag[I * 16 + k];
        float sk = __shfl(sv, sh | k);
        if (c16 > k) sv = fmaf(-row2[k], sk, sv);
      }
      Wf[(J * 16 + j16) * LDP + (I * 16 + c16)] = -sv;
    }
    lds_fence();
  }
}

extern "C" __global__ __launch_bounds__(NTH, 4)
void ide_kf_kernel(const float* __restrict__ z_seq,
                   const float* __restrict__ site_lon,
                   const float* __restrict__ site_lat,
                   const float* __restrict__ mu_seq,
                   const float* __restrict__ sigma_seq,
                   const float* __restrict__ log_q,
                   const float* __restrict__ log_r,
                   const float* __restrict__ log_p0,
                   const float* __restrict__ log_damp,
                   const float* __restrict__ init_mean,
                   const float* __restrict__ coupling_raw,
                   float* __restrict__ ws) {
  extern __shared__ float smem[];
  float* Wf     = smem;                  // 17408 floats (fp32 chol space)
  float* B1f    = Wf + WFLOATS;          // 8704 floats (Mtb bf16 / Lhi)
  float* B2f    = B1f + 8704;            // 8704 floats (Pb bf16 / Llo)
  float* coords = B2f + 8704;            // 128
  float* mv     = coords + 128;          // 128 (posterior mean)
  float* vv     = mv + DQ;               // 128
  float* yv     = vv + DQ;               // 128
  float* mdiag  = yv + DQ;               // 128
  float* red    = mdiag + DQ;            // 16

  unsigned short* Tb  = (unsigned short*)Wf;            // bf16, stride LDB
  unsigned short* Ab2 = (unsigned short*)Wf + 17408;    // A bf16 (Wf upper)
  unsigned short* Mtb = (unsigned short*)B1f;           // M^T bf16
  unsigned short* Pb  = (unsigned short*)B2f;           // P bf16 (symmetric)
  unsigned short* Lhi = (unsigned short*)B1f;           // chol L hi (Mtb dead)
  unsigned short* Llo = (unsigned short*)B2f;           // chol L lo (Pb dead)

  const int tid = threadIdx.x;
  const int lane = tid & 63;
  const int wave = tid >> 6;
  const int rb = wave >> 1, ch = wave & 1;
  const int m16 = lane & 15, quad = lane >> 4;
  const int grp = wave >> 2, pass = wave & 3;
  const int b = blockIdx.x;
  float* nll_out = ws;

  const float r2 = __expf(2.0f * log_r[0]);
  const float q2 = __expf(2.0f * log_q[0]);
  const float p0sq = __expf(2.0f * log_p0[0]);
  const float damping = __expf(log_damp[0]);
  const float cpl00 = 1.0f + 0.25f * tanhf(coupling_raw[0]);
  const float cpl01 = 0.25f * tanhf(coupling_raw[1]);
  const float cpl10 = 0.25f * tanhf(coupling_raw[2]);
  const float cpl11 = 1.0f + 0.25f * tanhf(coupling_raw[3]);

  // ---- lon/lat projection ----
  float myLon = (tid < SQ) ? site_lon[tid] : 0.0f;
  float myLat = (tid < SQ) ? site_lat[tid] : 0.0f;
  float lat0 = block_reduce_sum(myLat, red) * (1.0f / 64.0f);
  float lon0 = block_reduce_sum(myLon, red) * (1.0f / 64.0f);
  if (tid < SQ) {
    const float km = 111.32f;
    float cs = cosf(lat0 * 0.017453292519943295f);
    coords[2 * tid]     = (myLon - lon0) * (km * cs);
    coords[2 * tid + 1] = (myLat - lat0) * km;
  }
  __syncthreads();
  float dsum = 0.0f, dcnt = 0.0f;
  for (int idx = tid; idx < SQ * SQ; idx += NTH) {
    int i = idx >> 6, j = idx & 63;
    float dx = coords[2 * i] - coords[2 * j];
    float dy = coords[2 * i + 1] - coords[2 * j + 1];
    float d = sqrtf(dx * dx + dy * dy + 1e-12f);
    dsum += d;
    if (d > 1e-6f) dcnt += 1.0f;
  }
  dsum = block_reduce_sum(dsum, red);
  dcnt = block_reduce_sum(dcnt, red);
  float scale = dsum / fmaxf(dcnt, 1.0f);
  float sdiv = 1.0f / fmaxf(scale, 1e-6f);
  if (tid < SQ) { coords[2 * tid] *= sdiv; coords[2 * tid + 1] *= sdiv; }

  // ---- init: Wf = (p0sq+r2) I, mv = init_mean ----
  for (int e = tid; e < WFLOATS / 4; e += NTH)
    ((float4*)Wf)[e] = make_float4(0.0f, 0.0f, 0.0f, 0.0f);
  for (int e = tid; e < 8704 / 4; e += NTH)
    ((float4*)B2f)[e] = make_float4(0.0f, 0.0f, 0.0f, 0.0f);
  __syncthreads();
  if (tid < DQ) {
    Wf[tid * LDP + tid] = p0sq + r2;
    mv[tid] = init_mean[tid];
  }
  __syncthreads();

  float nllp = 0.0f;

  #pragma unroll 1
  for (int t = 0; t < TQ; t++) {
    const float* zt = z_seq + ((size_t)b * TQ + t) * DQ;

    if (t > 0) {
      // ---- PHASE T: mfma T = A*P -> Tb (single barrier) ----
      {
        f32x4 acc[4];
        #pragma unroll
        for (int c = 0; c < 4; c++) acc[c] = (f32x4){0.0f, 0.0f, 0.0f, 0.0f};
        #pragma unroll
        for (int ks = 0; ks < 4; ks++) {
          const int ko = 32 * ks + 8 * quad;
          bf16x8 a = *(const bf16x8*)(Ab2 + (16 * rb + m16) * LDB + ko);
          #pragma unroll
          for (int ct = 0; ct < 4; ct++) {
            bf16x8 bb = *(const bf16x8*)(Pb + (64 * ch + 16 * ct + m16) * LDB + ko);
            acc[ct] = __builtin_amdgcn_mfma_f32_16x16x32_bf16(a, bb, acc[ct], 0, 0, 0);
          }
        }
        #pragma unroll
        for (int ct = 0; ct < 4; ct++)
          #pragma unroll
          for (int reg = 0; reg < 4; reg++)
            Tb[(16 * rb + 4 * quad + reg) * LDB + 64 * ch + 16 * ct + m16] =
                f2bf(acc[ct][reg]);
        __syncthreads();
      }

      // ---- PHASE P': part1: Sm MFMA + m-GEMV (idle waves 1,3);
      //      midbar; part2: fp32 Wf + wave0 chol16_f(0) + vv ----
      {
        const int ctmax = rb - 4 * ch;
        f32x4 acc[4];
        #pragma unroll
        for (int c = 0; c < 4; c++) acc[c] = (f32x4){0.0f, 0.0f, 0.0f, 0.0f};
        const bool gemv_wave = (wave == 1 || wave == 3);
        const int grow = (wave == 1) ? lane : 64 + lane;
        float newm = 0.0f;
        if (ctmax >= 0) {
          #pragma unroll
          for (int ks = 0; ks < 4; ks++) {
            const int ko = 32 * ks + 8 * quad;
            bf16x8 a = *(const bf16x8*)(Tb + (16 * rb + m16) * LDB + ko);
            #pragma unroll
            for (int ct = 0; ct < 4; ct++) {
              if (ct <= ctmax) {
                bf16x8 bb = *(const bf16x8*)(Ab2 + (64 * ch + 16 * ct + m16) * LDB + ko);
                acc[ct] = __builtin_amdgcn_mfma_f32_16x16x32_bf16(a, bb, acc[ct], 0, 0, 0);
              }
            }
          }
        } else if (gemv_wave) {
          const unsigned* ar = (const unsigned*)(Ab2 + grow * LDB);
          #pragma unroll 8
          for (int k2 = 0; k2 < 64; k2++) {
            unsigned p = ar[k2];
            newm = fmaf(__uint_as_float(p << 16), mv[2 * k2], newm);
            newm = fmaf(__uint_as_float(p & 0xffff0000u), mv[2 * k2 + 1], newm);
          }
        }
        __syncthreads();   // Tb/Ab2 reads done
        if (ctmax >= 0) {
          #pragma unroll
          for (int ct = 0; ct < 4; ct++) {
            if (ct <= ctmax) {
              #pragma unroll
              for (int reg = 0; reg < 4; reg++) {
                const int rg = 16 * rb + 4 * quad + reg;
                const int cgl = 64 * ch + 16 * ct + m16;
                Wf[rg * LDP + cgl] = acc[ct][reg] + ((rg == cgl) ? (q2 + r2) : 0.0f);
              }
            }
          }
        }
        if (gemv_wave) vv[grow] = zt[grow] - newm;
        if (wave == 0) {
          lds_fence();
          chol16_f(Wf, mdiag, 0, lane);
        }
        __syncthreads();
      }
    }

    if (t == 0) {
      // ---- K0 (t=0 only): wave0 chol diag0 ; vv ----
      if (tid < 64) {
        chol16_f(Wf, mdiag, 0, lane);
      } else if (tid < 192) {
        const int i = tid - 64;
        vv[i] = zt[i] - mv[i];
      }
      __syncthreads();
    }

    // ---- chol: LEFT-LOOKING, split-bf16 MFMA column updates ----
    #pragma unroll 1
    for (int kb = 0; kb < 7; kb++) {
      const int b0k = kb * 16, base = b0k + 16, nbelow = DQ - base;
      // P1: TRSM rows base..127 vs diag kb + pack hi/lo + zero next slot
      if (tid < nbelow) {
        const int r = base + tid;
        float* wr = Wf + r * LDP + b0k;
        float w[16];
        #pragma unroll
        for (int u4 = 0; u4 < 4; u4++) {
          float4 w4 = *(const float4*)&wr[u4 * 4];
          w[u4*4] = w4.x; w[u4*4+1] = w4.y; w[u4*4+2] = w4.z; w[u4*4+3] = w4.w;
        }
        #pragma unroll
        for (int j = 0; j < 16; j++) {
          float s = w[j];
          #pragma unroll
          for (int l = 0; l < 16; l++) {
            if (l < j) s = fmaf(-w[l], Wf[(b0k + j) * LDP + b0k + l], s);
          }
          w[j] = s * mdiag[b0k + j];
        }
        #pragma unroll
        for (int u4 = 0; u4 < 4; u4++)
          *(float4*)&wr[u4 * 4] =
              make_float4(w[u4*4], w[u4*4+1], w[u4*4+2], w[u4*4+3]);
        // split-bf16 pack: w = hi + lo
        unsigned short hs[16]; float lo[16];
        #pragma unroll
        for (int u = 0; u < 16; u++) {
          hs[u] = f2bf(w[u]);
          lo[u] = w[u] - __uint_as_float(((unsigned)hs[u]) << 16);
        }
        uint4 h0, h1;
        h0.x = hs[0] | ((unsigned)hs[1] << 16);   h0.y = hs[2] | ((unsigned)hs[3] << 16);
        h0.z = hs[4] | ((unsigned)hs[5] << 16);   h0.w = hs[6] | ((unsigned)hs[7] << 16);
        h1.x = hs[8] | ((unsigned)hs[9] << 16);   h1.y = hs[10] | ((unsigned)hs[11] << 16);
        h1.z = hs[12] | ((unsigned)hs[13] << 16); h1.w = hs[14] | ((unsigned)hs[15] << 16);
        unsigned short* hr = Lhi + r * LDB + b0k;
        unsigned short* lr = Llo + r * LDB + b0k;
        *(uint4*)(hr) = h0; *(uint4*)(hr + 8) = h1;
        *(uint4*)(lr) = pack8(lo); *(uint4*)(lr + 8) = pack8(lo + 8);
        // zero next panel's column slot (odd-K chunk overshoot reads zeros)
        const uint4 z4 = make_uint4(0u, 0u, 0u, 0u);
        *(uint4*)(hr + 16) = z4; *(uint4*)(hr + 24) = z4;
        *(uint4*)(lr + 16) = z4; *(uint4*)(lr + 24) = z4;
      }
      __syncthreads();
      // P2: U(kb+1) tiles; wave0 diag + chol16; waves 8-11: Linv_kb solve
      if (wave <= 6 - kb) {
        const int bi = kb + 1 + wave;
        const int nch = (kb + 2) >> 1;   // ceil(16(kb+1)/32)
        f32x4 acc = (f32x4){0.0f, 0.0f, 0.0f, 0.0f};
        for (int c = 0; c < nch; c++) {
          const int ko = 32 * c + 8 * quad;
          bf16x8 ahi = *(const bf16x8*)(Lhi + (16 * bi + m16) * LDB + ko);
          bf16x8 alo = *(const bf16x8*)(Llo + (16 * bi + m16) * LDB + ko);
          bf16x8 bhi = *(const bf16x8*)(Lhi + (base + m16) * LDB + ko);
          bf16x8 blo = *(const bf16x8*)(Llo + (base + m16) * LDB + ko);
          acc = __builtin_amdgcn_mfma_f32_16x16x32_bf16(ahi, bhi, acc, 0, 0, 0);
          acc = __builtin_amdgcn_mfma_f32_16x16x32_bf16(ahi, blo, acc, 0, 0, 0);
          acc = __builtin_amdgcn_mfma_f32_16x16x32_bf16(alo, bhi, acc, 0, 0, 0);
        }
        #pragma unroll
        for (int reg = 0; reg < 4; reg++)
          Wf[(16 * bi + 4 * quad + reg) * LDP + base + m16] -= acc[reg];
        if (wave == 0) {
          lds_fence();
          chol16_f(Wf, mdiag, base, lane);
        }
      } else if (wave >= 8 && wave <= 11) {
        // Linv_kb column solve (pass = wave-8) -> diag-kb upper.
        const int c16 = lane & 15;
        const int j16s = 4 * (lane >> 4) + (wave - 8);
        const int sh = lane & 48;
        float row[16];
        const float4* rp = (const float4*)(Wf + (b0k + c16) * LDP + b0k);
        float4 a0 = rp[0], a1 = rp[1], a2 = rp[2], a3 = rp[3];
        row[0]=a0.x; row[1]=a0.y; row[2]=a0.z; row[3]=a0.w;
        row[4]=a1.x; row[5]=a1.y; row[6]=a1.z; row[7]=a1.w;
        row[8]=a2.x; row[9]=a2.y; row[10]=a2.z; row[11]=a2.w;
        row[12]=a3.x; row[13]=a3.y; row[14]=a3.z; row[15]=a3.w;
        float s = (c16 == j16s) ? 1.0f : 0.0f;
        #pragma unroll
        for (int k = 0; k < 16; k++) {
          if (c16 == k) s *= mdiag[b0k + k];
          float sk = __shfl(s, sh | k);
          if (c16 > k) s = fmaf(-row[k], sk, s);
        }
        if (c16 > j16s) Wf[(b0k + j16s) * LDP + (b0k + c16)] = s;
      }
      __syncthreads();
    }

    // ---- trinv: single barrier; Linv pre-hoisted (J=0..6); fast I-apply ----
    {
      #pragma unroll 1
      for (int cc = 0; cc < 2; cc++) {
        const int J = cc ? (7 - grp) : grp;
        trinv_chain2(Wf, mdiag, J, pass, lane, cc == 1 && grp == 0);
      }
      __syncthreads();
    }

    // ---- PHASE MC (single barrier): y=Mv + logdet; pack M^T -> Mtb ----
    {
      const int mrow = tid >> 3, kc = (tid & 7) * 16;
      float mtv[16];
      if (kc > mrow) {
        const float4* rp = (const float4*)(Wf + mrow * LDP + kc);
        float4 q0 = rp[0], q1 = rp[1], q2v = rp[2], q3 = rp[3];
        mtv[0]=q0.x; mtv[1]=q0.y; mtv[2]=q0.z; mtv[3]=q0.w;
        mtv[4]=q1.x; mtv[5]=q1.y; mtv[6]=q1.z; mtv[7]=q1.w;
        mtv[8]=q2v.x; mtv[9]=q2v.y; mtv[10]=q2v.z; mtv[11]=q2v.w;
        mtv[12]=q3.x; mtv[13]=q3.y; mtv[14]=q3.z; mtv[15]=q3.w;
      } else if (kc + 15 < mrow) {
        #pragma unroll
        for (int u = 0; u < 16; u++) mtv[u] = 0.0f;
      } else {
        #pragma unroll
        for (int u = 0; u < 16; u++) {
          const int k = kc + u;
          mtv[u] = (k > mrow) ? Wf[mrow * LDP + k]
                 : ((k == mrow) ? mdiag[mrow] : 0.0f);
        }
      }
      if (tid < DQ) {
        nllp -= __logf(mdiag[tid]);
        float s = mdiag[tid] * vv[tid];
        for (int k = 0; k < tid; k++) s = fmaf(Wf[k * LDP + tid], vv[k], s);
        yv[tid] = s;
      }
      unsigned short* mt = Mtb + mrow * LDB + kc;
      *(uint4*)(mt) = pack8(mtv);
      *(uint4*)(mt + 8) = pack8(mtv + 8);
      __syncthreads();
    }

    // ---- PHASE Pn (+fused A-build for step t+1): Sinv = M^T*M (lower);
    //      Pb = r2 I - r2^2 Sinv; m_post = z_t - r2*(Sinv v) -> mv;
    //      A(t+1) -> Ab2 ----
    {
      f32x4 acc[4];
      #pragma unroll
      for (int c = 0; c < 4; c++) acc[c] = (f32x4){0.0f, 0.0f, 0.0f, 0.0f};
      if (tid < DQ) nllp += 0.5f * yv[tid] * yv[tid];
      const int ctmax = rb - 4 * ch;
      if (ctmax >= 0) {
        for (int ks = (rb >> 1); ks < 4; ks++) {
          const int ko = 32 * ks + 8 * quad;
          bf16x8 a = *(const bf16x8*)(Mtb + (16 * rb + m16) * LDB + ko);
          #pragma unroll
          for (int ct = 0; ct < 4; ct++) {
            if (ct <= ctmax) {
              bf16x8 bb = *(const bf16x8*)(Mtb + (64 * ch + 16 * ct + m16) * LDB + ko);
              acc[ct] = __builtin_amdgcn_mfma_f32_16x16x32_bf16(a, bb, acc[ct], 0, 0, 0);
            }
          }
        }
      }
      const float nr22 = -r2 * r2;
      #pragma unroll
      for (int ct = 0; ct < 4; ct++) {
        if (ct <= ctmax) {
          const bool strict = (ct < ctmax);
          #pragma unroll
          for (int reg = 0; reg < 4; reg++) {
            const int rg = 16 * rb + 4 * quad + reg;
            const int cgl = 64 * ch + 16 * ct + m16;
            unsigned short hv = f2bf(nr22 * acc[ct][reg] + ((rg == cgl) ? r2 : 0.0f));
            Pb[rg * LDB + cgl] = hv;
            if (strict) Pb[cgl * LDB + rg] = hv;
          }
        }
      }
      if (tid < DQ) {
        const unsigned* mr = (const unsigned*)(Mtb + tid * LDB);
        float s = 0.0f;
        #pragma unroll 8
        for (int k2 = 0; k2 < 64; k2++) {
          unsigned p = mr[k2];
          s = fmaf(__uint_as_float(p << 16), yv[2 * k2], s);
          s = fmaf(__uint_as_float(p & 0xffff0000u), yv[2 * k2 + 1], s);
        }
        mv[tid] = zt[tid] - r2 * s;   // m_post = z - r2 * Sinv v
      }
      // ---- fused A-build for step t+1 (inputs only; independent) ----
      if (t < TQ - 1) {
        const float* mu_t = mu_seq + ((size_t)b * (TQ - 1) + t) * 4;
        const float* sg_t = sigma_seq + ((size_t)b * (TQ - 1) + t) * 16;
        const int unit = tid >> 2, q = tid & 3;
        const int r = unit >> 1, ss = unit & 1, tt = r >> 6, i = r & 63;
        float m0 = mu_t[0], m1 = mu_t[1], m2 = mu_t[2], m3 = mu_t[3];
        float dmx, dmy, c00, c01, c11;
        if (tt == 0 && ss == 0) {
          dmx = m0; dmy = m1;
          c00 = sg_t[0]; c01 = 0.5f * (sg_t[1] + sg_t[4]); c11 = sg_t[5];
        } else if (tt == 1 && ss == 1) {
          dmx = m2; dmy = m3;
          c00 = sg_t[10]; c01 = 0.5f * (sg_t[11] + sg_t[14]); c11 = sg_t[15];
        } else {
          dmx = 0.5f * (m0 + m2); dmy = 0.5f * (m1 + m3);
          float s00 = sg_t[0];
          float s02 = 0.5f * (sg_t[2] + sg_t[8]);
          float s22 = sg_t[10];
          float s01 = 0.5f * (sg_t[1] + sg_t[4]);
          float s03 = 0.5f * (sg_t[3] + sg_t[12]);
          float s21 = 0.5f * (sg_t[9] + sg_t[6]);
          float s23 = 0.5f * (sg_t[11] + sg_t[14]);
          float s11 = sg_t[5];
          float s13 = 0.5f * (sg_t[7] + sg_t[13]);
          float s33 = sg_t[15];
          c00 = 0.25f * (s00 + s02 + s02 + s22);
          c01 = 0.25f * (s01 + s03 + s21 + s23);
          c11 = 0.25f * (s11 + s13 + s13 + s33);
        }
        float D00 = 1.0001f + 2.0f * c00;
        float D01 = 2.0f * c01;
        float D11 = 1.0001f + 2.0f * c11;
        float det = D00 * D11 - D01 * D01;
        float dinv = 1.0f / det;
        float d00 = D11 * dinv, d01 = -D01 * dinv, d11 = D00 * dinv;
        float ldts = __logf(det);
        float cix = coords[2 * i], ciy = coords[2 * i + 1];
        const float* cj = coords + q * 32;
        float kv[16];
        float rsum = 0.0f;
        #pragma unroll
        for (int u = 0; u < 16; u++) {
          float dx = cix - cj[2 * u] - dmx;
          float dy = ciy - cj[2 * u + 1] - dmy;
          float qf = d00 * dx * dx + 2.0f * d01 * dx * dy + d11 * dy * dy;
          kv[u] = __expf(-0.5f * (qf + ldts));
          rsum += kv[u];
        }
        float rtot = rsum + __shfl_xor(rsum, 1);
        rtot += __shfl_xor(rtot, 2);
        float cv = (tt == 0) ? ((ss == 0) ? cpl00 : cpl01)
                             : ((ss == 0) ? cpl10 : cpl11);
        float norm = cv / fmaxf(rtot, 1e-6f);
        #pragma unroll
        for (int u = 0; u < 16; u++) kv[u] *= norm;
        if (ss == tt && ((i >> 4) == q)) kv[i & 15] += 1.0f - damping;
        unsigned short* arow = Ab2 + r * LDB + ss * 64 + q * 16;
        *(uint4*)(arow) = pack8(kv);
        *(uint4*)(arow + 8) = pack8(kv + 8);
      }
      __syncthreads();
    }
  }

  float total = block_reduce_sum(nllp, red);
  if (tid == 0)
    nll_out[b] = total + (float)TQ * 0.5f * (float)DQ * LOG2PI;
}

extern "C" __global__ void ide_finalize(const float* __restrict__ part,
                                        float* __restrict__ out) {
  if (threadIdx.x == 0) {
    float s = 0.0f;
    for (int i = 0; i < BQ; i++) s += part[i];
    out[0] = s * (1.0f / BQ);
  }
}

extern "C" void kernel_launch(void* const* d_in, const int* in_sizes, int n_in,
                              void* d_out, int out_size, void* d_ws, size_t ws_size,
                              hipStream_t stream) {
  (void)in_sizes; (void)n_in; (void)out_size; (void)ws_size;
  const float* z_seq        = (const float*)d_in[0];
  const float* site_lon     = (const float*)d_in[1];
  const float* site_lat     = (const float*)d_in[2];
  const float* mu_seq       = (const float*)d_in[3];
  const float* sigma_seq    = (const float*)d_in[4];
  const float* log_q        = (const float*)d_in[5];
  const float* log_r        = (const float*)d_in[6];
  const float* log_p0       = (const float*)d_in[7];
  const float* log_damp     = (const float*)d_in[8];
  const float* init_mean    = (const float*)d_in[9];
  const float* coupling_raw = (const float*)d_in[10];
  float* ws = (float*)d_ws;
  float* out = (float*)d_out;

  const size_t smem_bytes = (size_t)SMEM_FLOATS * sizeof(float);
  hipFuncSetAttribute((const void*)ide_kf_kernel,
                      hipFuncAttributeMaxDynamicSharedMemorySize,
                      (int)smem_bytes);

  hipLaunchKernelGGL(ide_kf_kernel, dim3(BQ), dim3(NTH), smem_bytes, stream,
                     z_seq, site_lon, site_lat, mu_seq, sigma_seq,
                     log_q, log_r, log_p0, log_damp, init_mean, coupling_raw,
                     ws);
  hipLaunchKernelGGL(ide_finalize, dim3(1), dim3(64), 0, stream, ws, out);
}